// Round 2
// baseline (2989.972 us; speedup 1.0000x reference)
//
#include <hip/hip_runtime.h>
#include <hip/hip_cooperative_groups.h>

namespace cg = cooperative_groups;

typedef __attribute__((ext_vector_type(4))) float f32x4;
typedef __attribute__((ext_vector_type(8))) short short8;
typedef __attribute__((ext_vector_type(4))) short short4v;
typedef unsigned short u16;

#define DEV static __device__ __forceinline__

DEV float bf2f(u16 u){ union { unsigned int i; float f; } v; v.i = ((unsigned int)u) << 16; return v.f; }
DEV u16 f2bf(float f){ union { float f; unsigned int i; } v; v.f = f; unsigned int r = v.i + 0x7fffu + ((v.i >> 16) & 1u); return (u16)(r >> 16); }
DEV float sigm(float x){ return 1.f / (1.f + expf(-x)); }

DEV short8 cvt8(const float* __restrict__ p){
    const f32x4* q = (const f32x4*)p;
    f32x4 lo = q[0], hi = q[1];
    short8 r;
    r[0]=(short)f2bf(lo[0]); r[1]=(short)f2bf(lo[1]); r[2]=(short)f2bf(lo[2]); r[3]=(short)f2bf(lo[3]);
    r[4]=(short)f2bf(hi[0]); r[5]=(short)f2bf(hi[1]); r[6]=(short)f2bf(hi[2]); r[7]=(short)f2bf(hi[3]);
    return r;
}

// ---------------------------------------------------------------------------
// k_cvt: fp32 -> bf16 bulk convert (n multiple of 4)
// ---------------------------------------------------------------------------
__global__ void __launch_bounds__(256)
k_cvt(const float* __restrict__ src, u16* __restrict__ dst, int n)
{
    int i = (blockIdx.x * 256 + threadIdx.x) * 4;
    if (i + 3 < n) {
        f32x4 v = *(const f32x4*)(src + i);
        short4v o;
        o[0]=(short)f2bf(v[0]); o[1]=(short)f2bf(v[1]);
        o[2]=(short)f2bf(v[2]); o[3]=(short)f2bf(v[3]);
        *(short4v*)(dst + i) = o;
    }
}

// ---------------------------------------------------------------------------
// k_init: transpose W_attn_in -> WT (bf16), init c (fp32) and h bf16 buf0
// ---------------------------------------------------------------------------
__global__ void __launch_bounds__(256)
k_init(const float* __restrict__ Wai, const float* __restrict__ h0, const float* __restrict__ c0,
       u16* __restrict__ WT, float* __restrict__ cF, u16* __restrict__ hb)
{
    const int bid = blockIdx.x, tid = threadIdx.x;
    __shared__ u16 tl[64][65];
    if (bid < 256) {
        int ti = bid >> 4, tj = bid & 15;
        int rr = tid >> 2, cc = (tid & 3) * 16;
        for (int i = 0; i < 16; ++i)
            tl[rr][cc + i] = f2bf(Wai[(size_t)(ti * 64 + rr) * 1024 + tj * 64 + cc + i]);
        __syncthreads();
        for (int i = 0; i < 16; ++i)
            WT[(size_t)(tj * 64 + rr) * 1024 + ti * 64 + cc + i] = tl[cc + i][rr];
    } else if (bid < 288) {
        int b = bid - 256;
        int j = tid * 4;
        for (int i = 0; i < 4; ++i) {
            int k = j + i;
            float hv = (k < 512) ? h0[(size_t)b * 512 + k] : h0[(size_t)(32 + b) * 512 + (k - 512)];
            float cv = (k < 512) ? c0[(size_t)b * 512 + k] : c0[(size_t)(32 + b) * 512 + (k - 512)];
            cF[b * 1024 + k] = cv;
            hb[b * 1024 + k] = f2bf(hv);   // buffer 0 = h_0
        }
    }
}

// ---------------------------------------------------------------------------
// k_xg: xg[r=t*32+b][m] = emb[tgt[b][t]] @ W_ih^T + b_ih + b_hh  (bf16 out)
// grid 2048 = 32 Mtiles x 64 Ntiles, tile 64x64, 4 waves
// ---------------------------------------------------------------------------
__global__ void __launch_bounds__(256)
k_xg(const int* __restrict__ tgt, const float* __restrict__ emb,
     const u16* __restrict__ Wih16, const float* __restrict__ bih, const float* __restrict__ bhh,
     u16* __restrict__ xg)
{
    const int bid = blockIdx.x, tid = threadIdx.x;
    const int mt = bid & 31, nt = bid >> 5;
    const int wv = tid >> 6, l = tid & 63, lr = l & 15, lq = l >> 4;
    const int r0 = mt * 64 + wv * 16;
    const int n0 = nt * 64;
    int r = r0 + lr;
    int rc = (r < 2016) ? r : 2015;
    int t = rc >> 5, b = rc & 31;
    const float* arow = emb + (size_t)tgt[b * 64 + t] * 1024;
    const u16* brow = Wih16 + (size_t)(n0 + lr) * 1024;
    f32x4 acc[4] = {{0,0,0,0},{0,0,0,0},{0,0,0,0},{0,0,0,0}};
    for (int k0 = 0; k0 < 1024; k0 += 32) {
        int ko = k0 + lq * 8;
        short8 av = cvt8(arow + ko);
#pragma unroll
        for (int nf = 0; nf < 4; ++nf) {
            short8 bv = *(const short8*)(brow + (size_t)nf * 16 * 1024 + ko);
            acc[nf] = __builtin_amdgcn_mfma_f32_16x16x32_bf16(av, bv, acc[nf], 0, 0, 0);
        }
    }
#pragma unroll
    for (int nf = 0; nf < 4; ++nf) {
        int n = n0 + nf * 16 + lr;
        float bias = bih[n] + bhh[n];
#pragma unroll
        for (int q = 0; q < 4; ++q) {
            int rr = r0 + lq * 4 + q;
            if (rr < 2016) xg[(size_t)rr * 4096 + n] = f2bf(acc[nf][q] + bias);
        }
    }
}

// ---------------------------------------------------------------------------
// k_M: M[r=b*128+s][k] = sum_j enc[r][j] * W_attn_in[j][k]  (fp32 out)
// grid 1024 = 64 Mtiles x 16 Ntiles
// ---------------------------------------------------------------------------
__global__ void __launch_bounds__(256)
k_M(const float* __restrict__ enc, const u16* __restrict__ WT, float* __restrict__ Mf)
{
    const int bid = blockIdx.x, tid = threadIdx.x;
    const int mt = bid & 63, nt = bid >> 6;
    const int wv = tid >> 6, l = tid & 63, lr = l & 15, lq = l >> 4;
    const int r0 = mt * 64 + wv * 16;
    const int n0 = nt * 64;
    const float* arow = enc + (size_t)(r0 + lr) * 1024;
    const u16* brow = WT + (size_t)(n0 + lr) * 1024;
    f32x4 acc[4] = {{0,0,0,0},{0,0,0,0},{0,0,0,0},{0,0,0,0}};
    for (int k0 = 0; k0 < 1024; k0 += 32) {
        int ko = k0 + lq * 8;
        short8 av = cvt8(arow + ko);
#pragma unroll
        for (int nf = 0; nf < 4; ++nf) {
            short8 bv = *(const short8*)(brow + (size_t)nf * 16 * 1024 + ko);
            acc[nf] = __builtin_amdgcn_mfma_f32_16x16x32_bf16(av, bv, acc[nf], 0, 0, 0);
        }
    }
#pragma unroll
    for (int nf = 0; nf < 4; ++nf) {
        int n = n0 + nf * 16 + lr;
#pragma unroll
        for (int q = 0; q < 4; ++q)
            Mf[(size_t)(r0 + lq * 4 + q) * 1024 + n] = acc[nf][q];
    }
}

// ---------------------------------------------------------------------------
// combine partial-softmax attention chunks -> ctxA[tstore] (bf16)
// ---------------------------------------------------------------------------
DEV void combine_ctx(int b, int tstore, int tid, int pidx,
                     const float* __restrict__ pCtx, const float* __restrict__ pMx,
                     const float* __restrict__ pSm, u16* __restrict__ ctxA)
{
    const float* mx = pMx + (size_t)pidx * 256 + b * 8;
    const float* sm = pSm + (size_t)pidx * 256 + b * 8;
    const float* pc = pCtx + (size_t)pidx * (32 * 8 * 1024) + (size_t)b * 8 * 1024;
    float gm = -1e30f;
#pragma unroll
    for (int c = 0; c < 8; ++c) gm = fmaxf(gm, mx[c]);
    float wsum = 0.f, e[8];
#pragma unroll
    for (int c = 0; c < 8; ++c) { e[c] = expf(mx[c] - gm); wsum += sm[c] * e[c]; }
    float inv = 1.f / wsum;
    int j = tid * 4;
    f32x4 a = {0.f, 0.f, 0.f, 0.f};
#pragma unroll
    for (int c = 0; c < 8; ++c) {
        f32x4 v = *(const f32x4*)(pc + (size_t)c * 1024 + j);
        float s = e[c] * inv;
        a[0] += v[0] * s; a[1] += v[1] * s; a[2] += v[2] * s; a[3] += v[3] * s;
    }
    short4v o4;
    o4[0] = (short)f2bf(a[0]); o4[1] = (short)f2bf(a[1]);
    o4[2] = (short)f2bf(a[2]); o4[3] = (short)f2bf(a[3]);
    *(short4v*)(ctxA + ((size_t)tstore * 32 + b) * 1024 + j) = o4;
}

// ---------------------------------------------------------------------------
// k_loop: persistent cooperative kernel. 256 blocks x 256 threads.
// super-step t: [combine(t-2)] + [gates GEMM+LSTM -> h_{t+1}] + [attn(t-1) partials], 1 grid sync
// ---------------------------------------------------------------------------
__global__ void __launch_bounds__(256, 1)
k_loop(const u16* __restrict__ xg, const float* __restrict__ Mf,
       u16* __restrict__ ctxA, u16* __restrict__ hAll,
       u16* __restrict__ hb, float* __restrict__ hF, float* __restrict__ cF,
       float* __restrict__ pCtx, float* __restrict__ pMx, float* __restrict__ pSm,
       const float* __restrict__ enc, const float* __restrict__ Whh,
       const int* __restrict__ slen, float* __restrict__ out)
{
    cg::grid_group grid = cg::this_grid();
    const int bid = blockIdx.x, tid = threadIdx.x;
    const int wv = tid >> 6, l = tid & 63, lr = l & 15, lq = l >> 4;

    __shared__ u16 Wl[16 * 1032];           // W_hh tile: 16 rows (padded +8), resident all 63 steps
    __shared__ float red[4][32][16];        // cross-wave GEMM partials
    __shared__ float hB[1024];              // h_{b_at} for attention
    __shared__ float scb[16], pb[16];

    // preload this block's 16 W_hh rows (row n = gate (n>>2), hidden col bid*4 + (n&3))
    {
        int n = tid >> 4;
        int cc = (tid & 15) * 64;
        const float* src = Whh + ((size_t)((n >> 2) * 1024 + bid * 4 + (n & 3))) * 1024 + cc;
        u16* dst = &Wl[n * 1032 + cc];
#pragma unroll
        for (int i = 0; i < 8; ++i)
            *(short8*)(dst + i * 8) = cvt8(src + i * 8);
    }
    __syncthreads();

    const int b_at = bid >> 3, ch = bid & 7, s0 = ch * 16;
    const int sc = tid >> 4, tj = tid & 15;
    int vlen = slen[b_at]; if (vlen < 1) vlen = 1;

    for (int t = 0; t < 64; ++t) {
        const int rd = t & 1, wr = rd ^ 1;

        if (t >= 2 && bid < 32)
            combine_ctx(bid, t - 2, tid, rd, pCtx, pMx, pSm, ctxA);

        if (t < 63) {
            // ---- gates GEMM: G[b, n] over this block's 16 gate-columns ----
            const u16* hrd = hb + (size_t)rd * (32 * 1024);
            f32x4 acc0 = {0,0,0,0}, acc1 = {0,0,0,0};
            const int kb = wv * 256;
#pragma unroll
            for (int ks = 0; ks < 8; ++ks) {
                int ko = kb + ks * 32 + lq * 8;
                short8 a0 = *(const short8*)(hrd + lr * 1024 + ko);
                short8 a1 = *(const short8*)(hrd + (16 + lr) * 1024 + ko);
                short8 bv = *(const short8*)(&Wl[lr * 1032 + ko]);
                acc0 = __builtin_amdgcn_mfma_f32_16x16x32_bf16(a0, bv, acc0, 0, 0, 0);
                acc1 = __builtin_amdgcn_mfma_f32_16x16x32_bf16(a1, bv, acc1, 0, 0, 0);
            }
#pragma unroll
            for (int q = 0; q < 4; ++q) {
                red[wv][lq * 4 + q][lr] = acc0[q];
                red[wv][16 + lq * 4 + q][lr] = acc1[q];
            }
        }
        __syncthreads();
        if (t < 63 && tid < 128) {
            // ---- LSTM elementwise for this block's 4 hidden columns ----
            int b = tid & 31, kk = tid >> 5;
            int kidx = bid * 4 + kk;
            float G[4];
#pragma unroll
            for (int g = 0; g < 4; ++g) {
                int n = g * 4 + kk;
                float s = red[0][b][n] + red[1][b][n] + red[2][b][n] + red[3][b][n];
                s += bf2f(xg[((size_t)t * 32 + b) * 4096 + g * 1024 + kidx]);
                G[g] = s;
            }
            float co = cF[b * 1024 + kidx];
            float iS = sigm(G[0]), fS = sigm(G[1]), gT = tanhf(G[2]), oS = sigm(G[3]);
            float cn = fS * co + iS * gT;
            float hn = oS * tanhf(cn);
            cF[b * 1024 + kidx] = cn;
            hF[(size_t)wr * (32 * 1024) + b * 1024 + kidx] = hn;
            u16 h16 = f2bf(hn);
            hb[(size_t)wr * (32 * 1024) + b * 1024 + kidx] = h16;
            hAll[((size_t)t * 32 + b) * 1024 + kidx] = h16;
        }

        if (t >= 1) {
            // ---- attention partials for step t-1 (uses h_t = hF[rd]) ----
            *(f32x4*)&hB[tid * 4] = *(const f32x4*)&hF[(size_t)rd * (32 * 1024) + b_at * 1024 + tid * 4];
            __syncthreads();
            int sg = s0 + sc;
            const float* Mr = Mf + ((size_t)(b_at * 128 + sg)) * 1024;
            float acc = 0.f;
#pragma unroll
            for (int it = 0; it < 16; ++it) {
                int j = tj * 64 + it * 4;
                f32x4 m4 = *(const f32x4*)&Mr[j];
                f32x4 h4 = *(const f32x4*)&hB[j];
                acc += m4[0]*h4[0] + m4[1]*h4[1] + m4[2]*h4[2] + m4[3]*h4[3];
            }
            acc += __shfl_xor(acc, 1);
            acc += __shfl_xor(acc, 2);
            acc += __shfl_xor(acc, 4);
            acc += __shfl_xor(acc, 8);
            if (tj == 0) scb[sc] = (sg < vlen) ? acc : -1e30f;
            __syncthreads();
            float mc = -1e30f;
#pragma unroll
            for (int s = 0; s < 16; ++s) mc = fmaxf(mc, scb[s]);
            if (tid < 16) {
                float sv = scb[tid];
                pb[tid] = (sv > -1e29f) ? expf(sv - mc) : 0.f;
            }
            __syncthreads();
            float psum = 0.f;
#pragma unroll
            for (int s = 0; s < 16; ++s) psum += pb[s];
            f32x4 ca = {0.f, 0.f, 0.f, 0.f};
            const float* eb = enc + ((size_t)(b_at * 128 + s0)) * 1024 + tid * 4;
#pragma unroll
            for (int s = 0; s < 16; ++s) {
                float p = pb[s];
                f32x4 e4 = *(const f32x4*)(eb + s * 1024);
                ca[0] += p * e4[0];
                ca[1] += p * e4[1];
                ca[2] += p * e4[2];
                ca[3] += p * e4[3];
            }
            *(f32x4*)&pCtx[(size_t)wr * (32 * 8 * 1024) + (size_t)(b_at * 8 + ch) * 1024 + tid * 4] = ca;
            if (tid == 0) { pMx[(size_t)wr * 256 + b_at * 8 + ch] = mc; pSm[(size_t)wr * 256 + b_at * 8 + ch] = psum; }
        }
        grid.sync();
    }

    // post-loop: last combine + final h/c outputs (fp32)
    if (bid < 32) {
        combine_ctx(bid, 62, tid, 0, pCtx, pMx, pSm, ctxA);
    } else if (bid < 64) {
        int b = bid - 32, j = tid * 4;
#pragma unroll
        for (int i = 0; i < 4; ++i)
            out[2064384 + b * 1024 + j + i] = hF[(size_t)1 * (32 * 1024) + b * 1024 + j + i];
    } else if (bid < 96) {
        int b = bid - 64, j = tid * 4;
#pragma unroll
        for (int i = 0; i < 4; ++i)
            out[2064384 + 32768 + b * 1024 + j + i] = cF[b * 1024 + j + i];
    }
}

// ---------------------------------------------------------------------------
// k_out: dec_out[b][t][n] = tanh( [ctx | h] @ W_attn_out^T ), K = 2048 (fp32 out)
// grid 512 = 32 Mtiles x 16 Ntiles
// ---------------------------------------------------------------------------
__global__ void __launch_bounds__(256)
k_out(const u16* __restrict__ ctxA, const u16* __restrict__ hAll,
      const u16* __restrict__ Wao16, float* __restrict__ out)
{
    const int bid = blockIdx.x, tid = threadIdx.x;
    const int mt = bid & 31, nt = bid >> 5;
    const int wv = tid >> 6, l = tid & 63, lr = l & 15, lq = l >> 4;
    const int r0 = mt * 64 + wv * 16;
    const int n0 = nt * 64;
    int r = r0 + lr;
    int rc = (r < 2016) ? r : 2015;
    const u16* arc = ctxA + (size_t)rc * 1024;
    const u16* arh = hAll + (size_t)rc * 1024;
    const u16* brow = Wao16 + (size_t)(n0 + lr) * 2048;
    f32x4 acc[4] = {{0,0,0,0},{0,0,0,0},{0,0,0,0},{0,0,0,0}};
    for (int k0 = 0; k0 < 2048; k0 += 32) {
        int ko = k0 + lq * 8;
        short8 av = (k0 < 1024) ? *(const short8*)(arc + ko)
                                : *(const short8*)(arh + (ko - 1024));
#pragma unroll
        for (int nf = 0; nf < 4; ++nf) {
            short8 bv = *(const short8*)(brow + (size_t)nf * 16 * 2048 + ko);
            acc[nf] = __builtin_amdgcn_mfma_f32_16x16x32_bf16(av, bv, acc[nf], 0, 0, 0);
        }
    }
#pragma unroll
    for (int nf = 0; nf < 4; ++nf) {
        int n = n0 + nf * 16 + lr;
#pragma unroll
        for (int q = 0; q < 4; ++q) {
            int rr = r0 + lq * 4 + q;
            if (rr < 2016) {
                int t = rr >> 5, b = rr & 31;
                out[(size_t)b * 64512 + t * 1024 + n] = tanhf(acc[nf][q]);
            }
        }
    }
}

// ---------------------------------------------------------------------------
extern "C" void kernel_launch(void* const* d_in, const int* in_sizes, int n_in,
                              void* d_out, int out_size, void* d_ws, size_t ws_size,
                              hipStream_t stream)
{
    (void)in_sizes; (void)n_in; (void)out_size; (void)ws_size;
    const int*   tgt  = (const int*)d_in[0];
    const float* h0   = (const float*)d_in[1];
    const float* c0   = (const float*)d_in[2];
    const float* enc  = (const float*)d_in[3];
    const int*   slen = (const int*)d_in[4];
    const float* emb  = (const float*)d_in[5];
    const float* Wih  = (const float*)d_in[6];
    const float* Whh  = (const float*)d_in[7];
    const float* bih  = (const float*)d_in[8];
    const float* bhh  = (const float*)d_in[9];
    const float* Wai  = (const float*)d_in[10];
    const float* Wao  = (const float*)d_in[11];
    float* out = (float*)d_out;

    char* ws = (char*)d_ws;
    size_t off = 0;
    auto alloc = [&](size_t bytes) -> char* {
        char* p = ws + off; off += (bytes + 255) & ~(size_t)255; return p;
    };
    u16*   xg    = (u16*)  alloc(63UL * 32 * 4096 * 2);
    float* Mf    = (float*)alloc(4096UL * 1024 * 4);
    u16*   WT    = (u16*)  alloc(1024UL * 1024 * 2);
    u16*   Wih16 = (u16*)  alloc(4096UL * 1024 * 2);
    u16*   Wao16 = (u16*)  alloc(1024UL * 2048 * 2);
    u16*   ctxA  = (u16*)  alloc(2016UL * 1024 * 2);
    u16*   hAll  = (u16*)  alloc(2016UL * 1024 * 2);
    u16*   hb    = (u16*)  alloc(2UL * 32 * 1024 * 2);
    float* hF    = (float*)alloc(2UL * 32 * 1024 * 4);
    float* cF    = (float*)alloc(32UL * 1024 * 4);
    float* pCtx  = (float*)alloc(2UL * 32 * 8 * 1024 * 4);
    float* pMx   = (float*)alloc(2UL * 32 * 8 * 4);
    float* pSm   = (float*)alloc(2UL * 32 * 8 * 4);

    hipLaunchKernelGGL(k_cvt, dim3(4096), dim3(256), 0, stream, Wih, Wih16, 4096 * 1024);
    hipLaunchKernelGGL(k_cvt, dim3(2048), dim3(256), 0, stream, Wao, Wao16, 1024 * 2048);
    hipLaunchKernelGGL(k_init, dim3(288), dim3(256), 0, stream, Wai, h0, c0, WT, cF, hb);
    hipLaunchKernelGGL(k_xg, dim3(2048), dim3(256), 0, stream, tgt, emb, Wih16, bih, bhh, xg);
    hipLaunchKernelGGL(k_M, dim3(1024), dim3(256), 0, stream, enc, WT, Mf);

    void* kargs[] = { (void*)&xg, (void*)&Mf, (void*)&ctxA, (void*)&hAll, (void*)&hb,
                      (void*)&hF, (void*)&cF, (void*)&pCtx, (void*)&pMx, (void*)&pSm,
                      (void*)&enc, (void*)&Whh, (void*)&slen, (void*)&out };
    hipLaunchCooperativeKernel((const void*)k_loop, dim3(256), dim3(256), kargs, 0, stream);

    hipLaunchKernelGGL(k_out, dim3(512), dim3(256), 0, stream, ctxA, hAll, Wao16, out);
}

// Round 3
// 2779.288 us; speedup vs baseline: 1.0758x; 1.0758x over previous
//
#include <hip/hip_runtime.h>
#include <hip/hip_cooperative_groups.h>

namespace cg = cooperative_groups;

typedef __attribute__((ext_vector_type(4))) float f32x4;
typedef __attribute__((ext_vector_type(8))) short short8;
typedef __attribute__((ext_vector_type(4))) short short4v;
typedef unsigned short u16;

#define DEV static __device__ __forceinline__

DEV float bf2f(u16 u){ union { unsigned int i; float f; } v; v.i = ((unsigned int)u) << 16; return v.f; }
DEV u16 f2bf(float f){ union { float f; unsigned int i; } v; v.f = f; unsigned int r = v.i + 0x7fffu + ((v.i >> 16) & 1u); return (u16)(r >> 16); }
DEV float sigm(float x){ return 1.f / (1.f + expf(-x)); }

DEV short8 cvt8(const float* __restrict__ p){
    const f32x4* q = (const f32x4*)p;
    f32x4 lo = q[0], hi = q[1];
    short8 r;
    r[0]=(short)f2bf(lo[0]); r[1]=(short)f2bf(lo[1]); r[2]=(short)f2bf(lo[2]); r[3]=(short)f2bf(lo[3]);
    r[4]=(short)f2bf(hi[0]); r[5]=(short)f2bf(hi[1]); r[6]=(short)f2bf(hi[2]); r[7]=(short)f2bf(hi[3]);
    return r;
}

// ---------------------------------------------------------------------------
// k_cvt: fp32 -> bf16 bulk convert (n multiple of 4)
// ---------------------------------------------------------------------------
__global__ void __launch_bounds__(256)
k_cvt(const float* __restrict__ src, u16* __restrict__ dst, int n)
{
    int i = (blockIdx.x * 256 + threadIdx.x) * 4;
    if (i + 3 < n) {
        f32x4 v = *(const f32x4*)(src + i);
        short4v o;
        o[0]=(short)f2bf(v[0]); o[1]=(short)f2bf(v[1]);
        o[2]=(short)f2bf(v[2]); o[3]=(short)f2bf(v[3]);
        *(short4v*)(dst + i) = o;
    }
}

// ---------------------------------------------------------------------------
// k_init: transpose W_attn_in -> WT (bf16), init c (fp32) and h bf16 buf0
// ---------------------------------------------------------------------------
__global__ void __launch_bounds__(256)
k_init(const float* __restrict__ Wai, const float* __restrict__ h0, const float* __restrict__ c0,
       u16* __restrict__ WT, float* __restrict__ cF, u16* __restrict__ hb)
{
    const int bid = blockIdx.x, tid = threadIdx.x;
    __shared__ u16 tl[64][65];
    if (bid < 256) {
        int ti = bid >> 4, tj = bid & 15;
        int rr = tid >> 2, cc = (tid & 3) * 16;
        for (int i = 0; i < 16; ++i)
            tl[rr][cc + i] = f2bf(Wai[(size_t)(ti * 64 + rr) * 1024 + tj * 64 + cc + i]);
        __syncthreads();
        for (int i = 0; i < 16; ++i)
            WT[(size_t)(tj * 64 + rr) * 1024 + ti * 64 + cc + i] = tl[cc + i][rr];
    } else if (bid < 288) {
        int b = bid - 256;
        int j = tid * 4;
        for (int i = 0; i < 4; ++i) {
            int k = j + i;
            float hv = (k < 512) ? h0[(size_t)b * 512 + k] : h0[(size_t)(32 + b) * 512 + (k - 512)];
            float cv = (k < 512) ? c0[(size_t)b * 512 + k] : c0[(size_t)(32 + b) * 512 + (k - 512)];
            cF[b * 1024 + k] = cv;
            hb[b * 1024 + k] = f2bf(hv);   // buffer 0 = h_0
        }
    }
}

// ---------------------------------------------------------------------------
// k_xg: xg[r=t*32+b][m] = emb[tgt[b][t]] @ W_ih^T + b_ih + b_hh  (bf16 out)
// ---------------------------------------------------------------------------
__global__ void __launch_bounds__(256)
k_xg(const int* __restrict__ tgt, const float* __restrict__ emb,
     const u16* __restrict__ Wih16, const float* __restrict__ bih, const float* __restrict__ bhh,
     u16* __restrict__ xg)
{
    const int bid = blockIdx.x, tid = threadIdx.x;
    const int mt = bid & 31, nt = bid >> 5;
    const int wv = tid >> 6, l = tid & 63, lr = l & 15, lq = l >> 4;
    const int r0 = mt * 64 + wv * 16;
    const int n0 = nt * 64;
    int r = r0 + lr;
    int rc = (r < 2016) ? r : 2015;
    int t = rc >> 5, b = rc & 31;
    const float* arow = emb + (size_t)tgt[b * 64 + t] * 1024;
    const u16* brow = Wih16 + (size_t)(n0 + lr) * 1024;
    f32x4 acc[4] = {{0,0,0,0},{0,0,0,0},{0,0,0,0},{0,0,0,0}};
    for (int k0 = 0; k0 < 1024; k0 += 32) {
        int ko = k0 + lq * 8;
        short8 av = cvt8(arow + ko);
#pragma unroll
        for (int nf = 0; nf < 4; ++nf) {
            short8 bv = *(const short8*)(brow + (size_t)nf * 16 * 1024 + ko);
            acc[nf] = __builtin_amdgcn_mfma_f32_16x16x32_bf16(av, bv, acc[nf], 0, 0, 0);
        }
    }
#pragma unroll
    for (int nf = 0; nf < 4; ++nf) {
        int n = n0 + nf * 16 + lr;
        float bias = bih[n] + bhh[n];
#pragma unroll
        for (int q = 0; q < 4; ++q) {
            int rr = r0 + lq * 4 + q;
            if (rr < 2016) xg[(size_t)rr * 4096 + n] = f2bf(acc[nf][q] + bias);
        }
    }
}

// ---------------------------------------------------------------------------
// k_M: M[r=b*128+s][k] = sum_j enc[r][j] * W_attn_in[j][k]  (fp32 out)
// ---------------------------------------------------------------------------
__global__ void __launch_bounds__(256)
k_M(const float* __restrict__ enc, const u16* __restrict__ WT, float* __restrict__ Mf)
{
    const int bid = blockIdx.x, tid = threadIdx.x;
    const int mt = bid & 63, nt = bid >> 6;
    const int wv = tid >> 6, l = tid & 63, lr = l & 15, lq = l >> 4;
    const int r0 = mt * 64 + wv * 16;
    const int n0 = nt * 64;
    const float* arow = enc + (size_t)(r0 + lr) * 1024;
    const u16* brow = WT + (size_t)(n0 + lr) * 1024;
    f32x4 acc[4] = {{0,0,0,0},{0,0,0,0},{0,0,0,0},{0,0,0,0}};
    for (int k0 = 0; k0 < 1024; k0 += 32) {
        int ko = k0 + lq * 8;
        short8 av = cvt8(arow + ko);
#pragma unroll
        for (int nf = 0; nf < 4; ++nf) {
            short8 bv = *(const short8*)(brow + (size_t)nf * 16 * 1024 + ko);
            acc[nf] = __builtin_amdgcn_mfma_f32_16x16x32_bf16(av, bv, acc[nf], 0, 0, 0);
        }
    }
#pragma unroll
    for (int nf = 0; nf < 4; ++nf) {
        int n = n0 + nf * 16 + lr;
#pragma unroll
        for (int q = 0; q < 4; ++q)
            Mf[(size_t)(r0 + lq * 4 + q) * 1024 + n] = acc[nf][q];
    }
}

// ---------------------------------------------------------------------------
// combine partial-softmax attention chunks -> ctxA[tstore] (bf16)
// ---------------------------------------------------------------------------
DEV void combine_ctx(int b, int tstore, int tid, int pidx,
                     const float* __restrict__ pCtx, const float* __restrict__ pMx,
                     const float* __restrict__ pSm, u16* __restrict__ ctxA)
{
    const float* mx = pMx + (size_t)pidx * 256 + b * 8;
    const float* sm = pSm + (size_t)pidx * 256 + b * 8;
    const float* pc = pCtx + (size_t)pidx * (32 * 8 * 1024) + (size_t)b * 8 * 1024;
    float gm = -1e30f;
#pragma unroll
    for (int c = 0; c < 8; ++c) gm = fmaxf(gm, mx[c]);
    float wsum = 0.f, e[8];
#pragma unroll
    for (int c = 0; c < 8; ++c) { e[c] = expf(mx[c] - gm); wsum += sm[c] * e[c]; }
    float inv = 1.f / wsum;
    int j = tid * 4;
    f32x4 a = {0.f, 0.f, 0.f, 0.f};
#pragma unroll
    for (int c = 0; c < 8; ++c) {
        f32x4 v = *(const f32x4*)(pc + (size_t)c * 1024 + j);
        float s = e[c] * inv;
        a[0] += v[0] * s; a[1] += v[1] * s; a[2] += v[2] * s; a[3] += v[3] * s;
    }
    short4v o4;
    o4[0] = (short)f2bf(a[0]); o4[1] = (short)f2bf(a[1]);
    o4[2] = (short)f2bf(a[2]); o4[3] = (short)f2bf(a[3]);
    *(short4v*)(ctxA + ((size_t)tstore * 32 + b) * 1024 + j) = o4;
}

// ---------------------------------------------------------------------------
// k_loop: persistent cooperative kernel. 256 blocks x 256 threads.
// LDS-resident for the whole loop: W_hh tile (33KB), M slice fp32 (64KB),
// enc slice bf16 (33KB). Zero steady-state global re-streaming.
// ---------------------------------------------------------------------------
#define WL_PITCH 1032
#define ML_PITCH 1028
#define EL_PITCH 1032
#define WL_BYTES (16 * WL_PITCH * 2)
#define ML_BYTES (16 * ML_PITCH * 4)
#define EL_BYTES (16 * EL_PITCH * 2)
#define DYN_BYTES (WL_BYTES + ML_BYTES + EL_BYTES)

__global__ void __launch_bounds__(256, 1)
k_loop(const u16* __restrict__ xg, const float* __restrict__ Mf,
       u16* __restrict__ ctxA, u16* __restrict__ hAll,
       u16* __restrict__ hb, float* __restrict__ hF, float* __restrict__ cF,
       float* __restrict__ pCtx, float* __restrict__ pMx, float* __restrict__ pSm,
       const float* __restrict__ enc, const float* __restrict__ Whh,
       const int* __restrict__ slen, float* __restrict__ out)
{
    cg::grid_group grid = cg::this_grid();
    const int bid = blockIdx.x, tid = threadIdx.x;
    const int wv = tid >> 6, l = tid & 63, lr = l & 15, lq = l >> 4;

    extern __shared__ char smem[];
    u16*   Wl = (u16*)smem;                       // [16][WL_PITCH]
    float* Ml = (float*)(smem + WL_BYTES);        // [16][ML_PITCH]
    u16*   El = (u16*)(smem + WL_BYTES + ML_BYTES); // [16][EL_PITCH]

    __shared__ float red[4][32][16];
    __shared__ float hB[1024];
    __shared__ float scb[16], pb[16];

    const int b_at = bid >> 3, ch = bid & 7, s0 = ch * 16;
    const int sc = tid >> 4, tj = tid & 15;

    // ---- prologue: LDS-resident data ----
    {   // W_hh: row n = gate (n>>2), hidden col bid*4 + (n&3)
        int n = tid >> 4;
        int cc = (tid & 15) * 64;
        const float* src = Whh + ((size_t)((n >> 2) * 1024 + bid * 4 + (n & 3))) * 1024 + cc;
        u16* dst = &Wl[n * WL_PITCH + cc];
#pragma unroll
        for (int i = 0; i < 8; ++i)
            *(short8*)(dst + i * 8) = cvt8(src + i * 8);
    }
    {   // M slice rows [b_at*128+s0 .. +16), fp32
        int row = tid >> 4;
        const float* src = Mf + (size_t)(b_at * 128 + s0 + row) * 1024;
        float* dst = &Ml[row * ML_PITCH];
#pragma unroll
        for (int i = 0; i < 16; ++i) {
            int c = (tid & 15) * 4 + i * 64;
            *(f32x4*)(dst + c) = *(const f32x4*)(src + c);
        }
    }
    {   // enc slice rows (same), bf16
        int row = tid >> 4;
        const float* src = enc + (size_t)(b_at * 128 + s0 + row) * 1024;
        u16* dst = &El[row * EL_PITCH];
#pragma unroll
        for (int i = 0; i < 16; ++i) {
            int c = (tid & 15) * 4 + i * 64;
            f32x4 v = *(const f32x4*)(src + c);
            short4v o;
            o[0]=(short)f2bf(v[0]); o[1]=(short)f2bf(v[1]);
            o[2]=(short)f2bf(v[2]); o[3]=(short)f2bf(v[3]);
            *(short4v*)(dst + c) = o;
        }
    }
    __syncthreads();

    int vlen = slen[b_at]; if (vlen < 1) vlen = 1;

    for (int t = 0; t < 64; ++t) {
        const int rd = t & 1, wr = rd ^ 1;

        if (t >= 2 && bid < 32)
            combine_ctx(bid, t - 2, tid, rd, pCtx, pMx, pSm, ctxA);

        if (t < 63) {
            // ---- gates GEMM: this block's 16 gate-columns ----
            const u16* hrd = hb + (size_t)rd * (32 * 1024);
            f32x4 acc0 = {0,0,0,0}, acc1 = {0,0,0,0};
            const int kb = wv * 256;
#pragma unroll
            for (int ks = 0; ks < 8; ++ks) {
                int ko = kb + ks * 32 + lq * 8;
                short8 a0 = *(const short8*)(hrd + lr * 1024 + ko);
                short8 a1 = *(const short8*)(hrd + (16 + lr) * 1024 + ko);
                short8 bv = *(const short8*)(&Wl[lr * WL_PITCH + ko]);
                acc0 = __builtin_amdgcn_mfma_f32_16x16x32_bf16(a0, bv, acc0, 0, 0, 0);
                acc1 = __builtin_amdgcn_mfma_f32_16x16x32_bf16(a1, bv, acc1, 0, 0, 0);
            }
#pragma unroll
            for (int q = 0; q < 4; ++q) {
                red[wv][lq * 4 + q][lr] = acc0[q];
                red[wv][16 + lq * 4 + q][lr] = acc1[q];
            }
        }
        __syncthreads();
        if (t < 63 && tid < 128) {
            // ---- LSTM elementwise for this block's 4 hidden columns ----
            int b = tid & 31, kk = tid >> 5;
            int kidx = bid * 4 + kk;
            float G[4];
#pragma unroll
            for (int g = 0; g < 4; ++g) {
                int n = g * 4 + kk;
                float s = red[0][b][n] + red[1][b][n] + red[2][b][n] + red[3][b][n];
                s += bf2f(xg[((size_t)t * 32 + b) * 4096 + g * 1024 + kidx]);
                G[g] = s;
            }
            float co = cF[b * 1024 + kidx];
            float iS = sigm(G[0]), fS = sigm(G[1]), gT = tanhf(G[2]), oS = sigm(G[3]);
            float cn = fS * co + iS * gT;
            float hn = oS * tanhf(cn);
            cF[b * 1024 + kidx] = cn;
            hF[(size_t)wr * (32 * 1024) + b * 1024 + kidx] = hn;
            u16 h16 = f2bf(hn);
            hb[(size_t)wr * (32 * 1024) + b * 1024 + kidx] = h16;
            hAll[((size_t)t * 32 + b) * 1024 + kidx] = h16;
        }

        if (t >= 1) {
            // ---- attention partials for step t-1 (h_t = hF[rd]) ----
            *(f32x4*)&hB[tid * 4] = *(const f32x4*)&hF[(size_t)rd * (32 * 1024) + b_at * 1024 + tid * 4];
            __syncthreads();
            float acc = 0.f;
#pragma unroll
            for (int it = 0; it < 16; ++it) {
                int j = it * 64 + tj * 4;
                f32x4 m4 = *(const f32x4*)&Ml[sc * ML_PITCH + j];
                f32x4 h4 = *(const f32x4*)&hB[j];
                acc += m4[0]*h4[0] + m4[1]*h4[1] + m4[2]*h4[2] + m4[3]*h4[3];
            }
            acc += __shfl_xor(acc, 1);
            acc += __shfl_xor(acc, 2);
            acc += __shfl_xor(acc, 4);
            acc += __shfl_xor(acc, 8);
            int sg = s0 + sc;
            if (tj == 0) scb[sc] = (sg < vlen) ? acc : -1e30f;
            __syncthreads();
            float mc = -1e30f;
#pragma unroll
            for (int s = 0; s < 16; ++s) mc = fmaxf(mc, scb[s]);
            if (tid < 16) {
                float sv = scb[tid];
                pb[tid] = (sv > -1e29f) ? expf(sv - mc) : 0.f;
            }
            __syncthreads();
            float psum = 0.f;
#pragma unroll
            for (int s = 0; s < 16; ++s) psum += pb[s];
            f32x4 ca = {0.f, 0.f, 0.f, 0.f};
#pragma unroll
            for (int s = 0; s < 16; ++s) {
                float p = pb[s];
                short4v e4 = *(const short4v*)(&El[s * EL_PITCH + tid * 4]);
                ca[0] += p * bf2f((u16)e4[0]);
                ca[1] += p * bf2f((u16)e4[1]);
                ca[2] += p * bf2f((u16)e4[2]);
                ca[3] += p * bf2f((u16)e4[3]);
            }
            *(f32x4*)&pCtx[(size_t)wr * (32 * 8 * 1024) + (size_t)(b_at * 8 + ch) * 1024 + tid * 4] = ca;
            if (tid == 0) { pMx[(size_t)wr * 256 + b_at * 8 + ch] = mc; pSm[(size_t)wr * 256 + b_at * 8 + ch] = psum; }
        }
        grid.sync();
    }

    // post-loop: last combine + final h/c outputs (fp32)
    if (bid < 32) {
        combine_ctx(bid, 62, tid, 0, pCtx, pMx, pSm, ctxA);
    } else if (bid < 64) {
        int b = bid - 32, j = tid * 4;
#pragma unroll
        for (int i = 0; i < 4; ++i)
            out[2064384 + b * 1024 + j + i] = hF[(size_t)1 * (32 * 1024) + b * 1024 + j + i];
    } else if (bid < 96) {
        int b = bid - 64, j = tid * 4;
#pragma unroll
        for (int i = 0; i < 4; ++i)
            out[2064384 + 32768 + b * 1024 + j + i] = cF[b * 1024 + j + i];
    }
}

// ---------------------------------------------------------------------------
// k_out: dec_out[b][t][n] = tanh( [ctx | h] @ W_attn_out^T ), K = 2048 (fp32 out)
// ---------------------------------------------------------------------------
__global__ void __launch_bounds__(256)
k_out(const u16* __restrict__ ctxA, const u16* __restrict__ hAll,
      const u16* __restrict__ Wao16, float* __restrict__ out)
{
    const int bid = blockIdx.x, tid = threadIdx.x;
    const int mt = bid & 31, nt = bid >> 5;
    const int wv = tid >> 6, l = tid & 63, lr = l & 15, lq = l >> 4;
    const int r0 = mt * 64 + wv * 16;
    const int n0 = nt * 64;
    int r = r0 + lr;
    int rc = (r < 2016) ? r : 2015;
    const u16* arc = ctxA + (size_t)rc * 1024;
    const u16* arh = hAll + (size_t)rc * 1024;
    const u16* brow = Wao16 + (size_t)(n0 + lr) * 2048;
    f32x4 acc[4] = {{0,0,0,0},{0,0,0,0},{0,0,0,0},{0,0,0,0}};
    for (int k0 = 0; k0 < 2048; k0 += 32) {
        int ko = k0 + lq * 8;
        short8 av = (k0 < 1024) ? *(const short8*)(arc + ko)
                                : *(const short8*)(arh + (ko - 1024));
#pragma unroll
        for (int nf = 0; nf < 4; ++nf) {
            short8 bv = *(const short8*)(brow + (size_t)nf * 16 * 2048 + ko);
            acc[nf] = __builtin_amdgcn_mfma_f32_16x16x32_bf16(av, bv, acc[nf], 0, 0, 0);
        }
    }
#pragma unroll
    for (int nf = 0; nf < 4; ++nf) {
        int n = n0 + nf * 16 + lr;
#pragma unroll
        for (int q = 0; q < 4; ++q) {
            int rr = r0 + lq * 4 + q;
            if (rr < 2016) {
                int t = rr >> 5, b = rr & 31;
                out[(size_t)b * 64512 + t * 1024 + n] = tanhf(acc[nf][q]);
            }
        }
    }
}

// ---------------------------------------------------------------------------
extern "C" void kernel_launch(void* const* d_in, const int* in_sizes, int n_in,
                              void* d_out, int out_size, void* d_ws, size_t ws_size,
                              hipStream_t stream)
{
    (void)in_sizes; (void)n_in; (void)out_size; (void)ws_size;
    const int*   tgt  = (const int*)d_in[0];
    const float* h0   = (const float*)d_in[1];
    const float* c0   = (const float*)d_in[2];
    const float* enc  = (const float*)d_in[3];
    const int*   slen = (const int*)d_in[4];
    const float* emb  = (const float*)d_in[5];
    const float* Wih  = (const float*)d_in[6];
    const float* Whh  = (const float*)d_in[7];
    const float* bih  = (const float*)d_in[8];
    const float* bhh  = (const float*)d_in[9];
    const float* Wai  = (const float*)d_in[10];
    const float* Wao  = (const float*)d_in[11];
    float* out = (float*)d_out;

    char* ws = (char*)d_ws;
    size_t off = 0;
    auto alloc = [&](size_t bytes) -> char* {
        char* p = ws + off; off += (bytes + 255) & ~(size_t)255; return p;
    };
    u16*   xg    = (u16*)  alloc(63UL * 32 * 4096 * 2);
    float* Mf    = (float*)alloc(4096UL * 1024 * 4);
    u16*   WT    = (u16*)  alloc(1024UL * 1024 * 2);
    u16*   Wih16 = (u16*)  alloc(4096UL * 1024 * 2);
    u16*   Wao16 = (u16*)  alloc(1024UL * 2048 * 2);
    u16*   ctxA  = (u16*)  alloc(2016UL * 1024 * 2);
    u16*   hAll  = (u16*)  alloc(2016UL * 1024 * 2);
    u16*   hb    = (u16*)  alloc(2UL * 32 * 1024 * 2);
    float* hF    = (float*)alloc(2UL * 32 * 1024 * 4);
    float* cF    = (float*)alloc(32UL * 1024 * 4);
    float* pCtx  = (float*)alloc(2UL * 32 * 8 * 1024 * 4);
    float* pMx   = (float*)alloc(2UL * 32 * 8 * 4);
    float* pSm   = (float*)alloc(2UL * 32 * 8 * 4);

    static int lds_set = 0;
    if (!lds_set) {
        (void)hipFuncSetAttribute((const void*)k_loop,
                                  hipFuncAttributeMaxDynamicSharedMemorySize, DYN_BYTES);
        lds_set = 1;
    }

    hipLaunchKernelGGL(k_cvt, dim3(4096), dim3(256), 0, stream, Wih, Wih16, 4096 * 1024);
    hipLaunchKernelGGL(k_cvt, dim3(2048), dim3(256), 0, stream, Wao, Wao16, 1024 * 2048);
    hipLaunchKernelGGL(k_init, dim3(288), dim3(256), 0, stream, Wai, h0, c0, WT, cF, hb);
    hipLaunchKernelGGL(k_xg, dim3(2048), dim3(256), 0, stream, tgt, emb, Wih16, bih, bhh, xg);
    hipLaunchKernelGGL(k_M, dim3(1024), dim3(256), 0, stream, enc, WT, Mf);

    void* kargs[] = { (void*)&xg, (void*)&Mf, (void*)&ctxA, (void*)&hAll, (void*)&hb,
                      (void*)&hF, (void*)&cF, (void*)&pCtx, (void*)&pMx, (void*)&pSm,
                      (void*)&enc, (void*)&Whh, (void*)&slen, (void*)&out };
    hipLaunchCooperativeKernel((const void*)k_loop, dim3(256), dim3(256), kargs, DYN_BYTES, stream);

    hipLaunchKernelGGL(k_out, dim3(512), dim3(256), 0, stream, ctxA, hAll, Wao16, out);
}

// Round 4
// 1446.095 us; speedup vs baseline: 2.0676x; 1.9219x over previous
//
#include <hip/hip_runtime.h>

typedef __attribute__((ext_vector_type(4))) float f32x4;
typedef __attribute__((ext_vector_type(8))) short short8;
typedef __attribute__((ext_vector_type(4))) short short4v;
typedef unsigned short u16;
typedef unsigned int u32;

#define DEV static __device__ __forceinline__

DEV float bf2f(u16 u){ union { unsigned int i; float f; } v; v.i = ((unsigned int)u) << 16; return v.f; }
DEV u16 f2bf(float f){ union { float f; unsigned int i; } v; v.f = f; unsigned int r = v.i + 0x7fffu + ((v.i >> 16) & 1u); return (u16)(r >> 16); }
DEV float sigm(float x){ return 1.f / (1.f + expf(-x)); }

DEV short8 cvt8(const float* __restrict__ p){
    const f32x4* q = (const f32x4*)p;
    f32x4 lo = q[0], hi = q[1];
    short8 r;
    r[0]=(short)f2bf(lo[0]); r[1]=(short)f2bf(lo[1]); r[2]=(short)f2bf(lo[2]); r[3]=(short)f2bf(lo[3]);
    r[4]=(short)f2bf(hi[0]); r[5]=(short)f2bf(hi[1]); r[6]=(short)f2bf(hi[2]); r[7]=(short)f2bf(hi[3]);
    return r;
}

// ---------------------------------------------------------------------------
// Custom grid barrier: slot-per-block + leader publish. No contended atomics.
// slots[256] one u32 per block; gen at slots[320] (separate cacheline).
// ---------------------------------------------------------------------------
DEV void grid_bar(u32* __restrict__ slots, u32* __restrict__ gen,
                  u32 n, int bid, int tid)
{
    __syncthreads();   // all waves' global writes drained (vmcnt0) before release
    if (tid == 0)
        __hip_atomic_store(&slots[bid], n, __ATOMIC_RELEASE, __HIP_MEMORY_SCOPE_AGENT);
    if (bid == 0 && tid < 64) {
        for (;;) {
            u32 v0 = __hip_atomic_load(&slots[tid*4+0], __ATOMIC_RELAXED, __HIP_MEMORY_SCOPE_AGENT);
            u32 v1 = __hip_atomic_load(&slots[tid*4+1], __ATOMIC_RELAXED, __HIP_MEMORY_SCOPE_AGENT);
            u32 v2 = __hip_atomic_load(&slots[tid*4+2], __ATOMIC_RELAXED, __HIP_MEMORY_SCOPE_AGENT);
            u32 v3 = __hip_atomic_load(&slots[tid*4+3], __ATOMIC_RELAXED, __HIP_MEMORY_SCOPE_AGENT);
            bool ok = (v0 >= n) && (v1 >= n) && (v2 >= n) && (v3 >= n);
            if (__all(ok)) break;
            __builtin_amdgcn_s_sleep(2);
        }
        if (tid == 0)
            __hip_atomic_store(gen, n, __ATOMIC_RELEASE, __HIP_MEMORY_SCOPE_AGENT);
    }
    if (tid == 0) {
        while (__hip_atomic_load(gen, __ATOMIC_RELAXED, __HIP_MEMORY_SCOPE_AGENT) < n)
            __builtin_amdgcn_s_sleep(2);
        (void)__hip_atomic_load(gen, __ATOMIC_ACQUIRE, __HIP_MEMORY_SCOPE_AGENT); // L2 inv
    }
    __syncthreads();
}

// ---------------------------------------------------------------------------
// k_cvt: fp32 -> bf16 bulk convert (n multiple of 4)
// ---------------------------------------------------------------------------
__global__ void __launch_bounds__(256)
k_cvt(const float* __restrict__ src, u16* __restrict__ dst, int n)
{
    int i = (blockIdx.x * 256 + threadIdx.x) * 4;
    if (i + 3 < n) {
        f32x4 v = *(const f32x4*)(src + i);
        short4v o;
        o[0]=(short)f2bf(v[0]); o[1]=(short)f2bf(v[1]);
        o[2]=(short)f2bf(v[2]); o[3]=(short)f2bf(v[3]);
        *(short4v*)(dst + i) = o;
    }
}

// ---------------------------------------------------------------------------
// k_init: transpose W_attn_in -> WT (bf16), init c (fp32) and h bf16 buf0
// ---------------------------------------------------------------------------
__global__ void __launch_bounds__(256)
k_init(const float* __restrict__ Wai, const float* __restrict__ h0, const float* __restrict__ c0,
       u16* __restrict__ WT, float* __restrict__ cF, u16* __restrict__ hb)
{
    const int bid = blockIdx.x, tid = threadIdx.x;
    __shared__ u16 tl[64][65];
    if (bid < 256) {
        int ti = bid >> 4, tj = bid & 15;
        int rr = tid >> 2, cc = (tid & 3) * 16;
        for (int i = 0; i < 16; ++i)
            tl[rr][cc + i] = f2bf(Wai[(size_t)(ti * 64 + rr) * 1024 + tj * 64 + cc + i]);
        __syncthreads();
        for (int i = 0; i < 16; ++i)
            WT[(size_t)(tj * 64 + rr) * 1024 + ti * 64 + cc + i] = tl[cc + i][rr];
    } else if (bid < 288) {
        int b = bid - 256;
        int j = tid * 4;
        for (int i = 0; i < 4; ++i) {
            int k = j + i;
            float hv = (k < 512) ? h0[(size_t)b * 512 + k] : h0[(size_t)(32 + b) * 512 + (k - 512)];
            float cv = (k < 512) ? c0[(size_t)b * 512 + k] : c0[(size_t)(32 + b) * 512 + (k - 512)];
            cF[b * 1024 + k] = cv;
            hb[b * 1024 + k] = f2bf(hv);   // buffer 0 = h_0
        }
    }
}

// ---------------------------------------------------------------------------
// k_xg: xg[r=t*32+b][m] = emb[tgt[b][t]] @ W_ih^T + b_ih + b_hh  (bf16 out)
// ---------------------------------------------------------------------------
__global__ void __launch_bounds__(256)
k_xg(const int* __restrict__ tgt, const float* __restrict__ emb,
     const u16* __restrict__ Wih16, const float* __restrict__ bih, const float* __restrict__ bhh,
     u16* __restrict__ xg)
{
    const int bid = blockIdx.x, tid = threadIdx.x;
    const int mt = bid & 31, nt = bid >> 5;
    const int wv = tid >> 6, l = tid & 63, lr = l & 15, lq = l >> 4;
    const int r0 = mt * 64 + wv * 16;
    const int n0 = nt * 64;
    int r = r0 + lr;
    int rc = (r < 2016) ? r : 2015;
    int t = rc >> 5, b = rc & 31;
    const float* arow = emb + (size_t)tgt[b * 64 + t] * 1024;
    const u16* brow = Wih16 + (size_t)(n0 + lr) * 1024;
    f32x4 acc[4] = {{0,0,0,0},{0,0,0,0},{0,0,0,0},{0,0,0,0}};
    for (int k0 = 0; k0 < 1024; k0 += 32) {
        int ko = k0 + lq * 8;
        short8 av = cvt8(arow + ko);
#pragma unroll
        for (int nf = 0; nf < 4; ++nf) {
            short8 bv = *(const short8*)(brow + (size_t)nf * 16 * 1024 + ko);
            acc[nf] = __builtin_amdgcn_mfma_f32_16x16x32_bf16(av, bv, acc[nf], 0, 0, 0);
        }
    }
#pragma unroll
    for (int nf = 0; nf < 4; ++nf) {
        int n = n0 + nf * 16 + lr;
        float bias = bih[n] + bhh[n];
#pragma unroll
        for (int q = 0; q < 4; ++q) {
            int rr = r0 + lq * 4 + q;
            if (rr < 2016) xg[(size_t)rr * 4096 + n] = f2bf(acc[nf][q] + bias);
        }
    }
}

// ---------------------------------------------------------------------------
// k_M: M[r=b*128+s][k] = sum_j enc[r][j] * W_attn_in[j][k]  (fp32 out)
// ---------------------------------------------------------------------------
__global__ void __launch_bounds__(256)
k_M(const float* __restrict__ enc, const u16* __restrict__ WT, float* __restrict__ Mf)
{
    const int bid = blockIdx.x, tid = threadIdx.x;
    const int mt = bid & 63, nt = bid >> 6;
    const int wv = tid >> 6, l = tid & 63, lr = l & 15, lq = l >> 4;
    const int r0 = mt * 64 + wv * 16;
    const int n0 = nt * 64;
    const float* arow = enc + (size_t)(r0 + lr) * 1024;
    const u16* brow = WT + (size_t)(n0 + lr) * 1024;
    f32x4 acc[4] = {{0,0,0,0},{0,0,0,0},{0,0,0,0},{0,0,0,0}};
    for (int k0 = 0; k0 < 1024; k0 += 32) {
        int ko = k0 + lq * 8;
        short8 av = cvt8(arow + ko);
#pragma unroll
        for (int nf = 0; nf < 4; ++nf) {
            short8 bv = *(const short8*)(brow + (size_t)nf * 16 * 1024 + ko);
            acc[nf] = __builtin_amdgcn_mfma_f32_16x16x32_bf16(av, bv, acc[nf], 0, 0, 0);
        }
    }
#pragma unroll
    for (int nf = 0; nf < 4; ++nf) {
        int n = n0 + nf * 16 + lr;
#pragma unroll
        for (int q = 0; q < 4; ++q)
            Mf[(size_t)(r0 + lq * 4 + q) * 1024 + n] = acc[nf][q];
    }
}

// ---------------------------------------------------------------------------
// combine slice: block (b=bid>>3, ch=bid&7) combines 128 ctx elements of
// batch b for timestep tstore. tid<32 active (f32x4 each).
// ---------------------------------------------------------------------------
DEV void combine_slice(int b, int ch, int tstore, int tid, int pidx,
                       const float* __restrict__ pCtx, const float* __restrict__ pMx,
                       const float* __restrict__ pSm, u16* __restrict__ ctxA)
{
    if (tid >= 32) return;
    const float* mx = pMx + (size_t)pidx * 256 + b * 8;
    const float* sm = pSm + (size_t)pidx * 256 + b * 8;
    const float* pc = pCtx + (size_t)pidx * (32 * 8 * 1024) + (size_t)b * 8 * 1024;
    float gm = -1e30f;
#pragma unroll
    for (int c = 0; c < 8; ++c) gm = fmaxf(gm, mx[c]);
    float wsum = 0.f, e[8];
#pragma unroll
    for (int c = 0; c < 8; ++c) { e[c] = expf(mx[c] - gm); wsum += sm[c] * e[c]; }
    float inv = 1.f / wsum;
    int j = ch * 128 + tid * 4;
    f32x4 a = {0.f, 0.f, 0.f, 0.f};
#pragma unroll
    for (int c = 0; c < 8; ++c) {
        f32x4 v = *(const f32x4*)(pc + (size_t)c * 1024 + j);
        float s = e[c] * inv;
        a[0] += v[0] * s; a[1] += v[1] * s; a[2] += v[2] * s; a[3] += v[3] * s;
    }
    short4v o4;
    o4[0] = (short)f2bf(a[0]); o4[1] = (short)f2bf(a[1]);
    o4[2] = (short)f2bf(a[2]); o4[3] = (short)f2bf(a[3]);
    *(short4v*)(ctxA + ((size_t)tstore * 32 + b) * 1024 + j) = o4;
}

// ---------------------------------------------------------------------------
// k_loop: persistent cooperative kernel, custom grid barrier.
// LDS-resident: W_hh tile (33KB), M slice fp32 (64KB), enc slice bf16 (33KB).
// ---------------------------------------------------------------------------
#define WL_PITCH 1032
#define ML_PITCH 1028
#define EL_PITCH 1032
#define WL_BYTES (16 * WL_PITCH * 2)
#define ML_BYTES (16 * ML_PITCH * 4)
#define EL_BYTES (16 * EL_PITCH * 2)
#define DYN_BYTES (WL_BYTES + ML_BYTES + EL_BYTES)

__global__ void __launch_bounds__(256, 1)
k_loop(const u16* __restrict__ xg, const float* __restrict__ Mf,
       u16* __restrict__ ctxA, u16* __restrict__ hAll,
       u16* __restrict__ hb, float* __restrict__ hF, float* __restrict__ cF,
       float* __restrict__ pCtx, float* __restrict__ pMx, float* __restrict__ pSm,
       const float* __restrict__ enc, const float* __restrict__ Whh,
       const int* __restrict__ slen, float* __restrict__ out, u32* __restrict__ bar)
{
    const int bid = blockIdx.x, tid = threadIdx.x;
    const int wv = tid >> 6, l = tid & 63, lr = l & 15, lq = l >> 4;
    u32* slots = bar;
    u32* gen = bar + 320;

    extern __shared__ char smem[];
    u16*   Wl = (u16*)smem;                         // [16][WL_PITCH]
    float* Ml = (float*)(smem + WL_BYTES);          // [16][ML_PITCH]
    u16*   El = (u16*)(smem + WL_BYTES + ML_BYTES); // [16][EL_PITCH]

    __shared__ float red[4][32][16];
    __shared__ float hB[1024];
    __shared__ float scb[16], pb[16];

    const int b_at = bid >> 3, ch = bid & 7, s0 = ch * 16;
    const int sc = tid >> 4, tj = tid & 15;

    // ---- prologue: LDS-resident data ----
    {   // W_hh: row n = gate (n>>2), hidden col bid*4 + (n&3)
        int n = tid >> 4;
        int cc = (tid & 15) * 64;
        const float* src = Whh + ((size_t)((n >> 2) * 1024 + bid * 4 + (n & 3))) * 1024 + cc;
        u16* dst = &Wl[n * WL_PITCH + cc];
#pragma unroll
        for (int i = 0; i < 8; ++i)
            *(short8*)(dst + i * 8) = cvt8(src + i * 8);
    }
    {   // M slice rows [b_at*128+s0 .. +16), fp32
        int row = tid >> 4;
        const float* src = Mf + (size_t)(b_at * 128 + s0 + row) * 1024;
        float* dst = &Ml[row * ML_PITCH];
#pragma unroll
        for (int i = 0; i < 16; ++i) {
            int c = (tid & 15) * 4 + i * 64;
            *(f32x4*)(dst + c) = *(const f32x4*)(src + c);
        }
    }
    {   // enc slice rows (same), bf16
        int row = tid >> 4;
        const float* src = enc + (size_t)(b_at * 128 + s0 + row) * 1024;
        u16* dst = &El[row * EL_PITCH];
#pragma unroll
        for (int i = 0; i < 16; ++i) {
            int c = (tid & 15) * 4 + i * 64;
            f32x4 v = *(const f32x4*)(src + c);
            short4v o;
            o[0]=(short)f2bf(v[0]); o[1]=(short)f2bf(v[1]);
            o[2]=(short)f2bf(v[2]); o[3]=(short)f2bf(v[3]);
            *(short4v*)(dst + c) = o;
        }
    }
    __syncthreads();

    int vlen = slen[b_at]; if (vlen < 1) vlen = 1;

    for (int t = 0; t < 64; ++t) {
        const int rd = t & 1, wr = rd ^ 1;

        // prefetch xg for this step's LSTM (recurrence-independent; hides under GEMM)
        float xgv[4];
        if (t < 63 && tid < 128) {
            int b = tid & 31, kk = tid >> 5;
#pragma unroll
            for (int g = 0; g < 4; ++g)
                xgv[g] = bf2f(xg[((size_t)t * 32 + b) * 4096 + g * 1024 + bid * 4 + kk]);
        }

        if (t >= 2)
            combine_slice(b_at, ch, t - 2, tid, rd, pCtx, pMx, pSm, ctxA);

        if (t < 63) {
            // ---- gates GEMM: this block's 16 gate-columns ----
            const u16* hrd = hb + (size_t)rd * (32 * 1024);
            f32x4 acc0 = {0,0,0,0}, acc1 = {0,0,0,0};
            const int kb = wv * 256;
#pragma unroll
            for (int ks = 0; ks < 8; ++ks) {
                int ko = kb + ks * 32 + lq * 8;
                short8 a0 = *(const short8*)(hrd + lr * 1024 + ko);
                short8 a1 = *(const short8*)(hrd + (16 + lr) * 1024 + ko);
                short8 bv = *(const short8*)(&Wl[lr * WL_PITCH + ko]);
                acc0 = __builtin_amdgcn_mfma_f32_16x16x32_bf16(a0, bv, acc0, 0, 0, 0);
                acc1 = __builtin_amdgcn_mfma_f32_16x16x32_bf16(a1, bv, acc1, 0, 0, 0);
            }
#pragma unroll
            for (int q = 0; q < 4; ++q) {
                red[wv][lq * 4 + q][lr] = acc0[q];
                red[wv][16 + lq * 4 + q][lr] = acc1[q];
            }
        }
        __syncthreads();
        if (t < 63 && tid < 128) {
            // ---- LSTM elementwise for this block's 4 hidden columns ----
            int b = tid & 31, kk = tid >> 5;
            int kidx = bid * 4 + kk;
            float G[4];
#pragma unroll
            for (int g = 0; g < 4; ++g) {
                int n = g * 4 + kk;
                G[g] = red[0][b][n] + red[1][b][n] + red[2][b][n] + red[3][b][n] + xgv[g];
            }
            float co = cF[b * 1024 + kidx];
            float iS = sigm(G[0]), fS = sigm(G[1]), gT = tanhf(G[2]), oS = sigm(G[3]);
            float cn = fS * co + iS * gT;
            float hn = oS * tanhf(cn);
            cF[b * 1024 + kidx] = cn;
            hF[(size_t)wr * (32 * 1024) + b * 1024 + kidx] = hn;
            u16 h16 = f2bf(hn);
            hb[(size_t)wr * (32 * 1024) + b * 1024 + kidx] = h16;
            hAll[((size_t)t * 32 + b) * 1024 + kidx] = h16;
        }

        if (t >= 1) {
            // ---- attention partials for step t-1 (h_t = hF[rd]) ----
            *(f32x4*)&hB[tid * 4] = *(const f32x4*)&hF[(size_t)rd * (32 * 1024) + b_at * 1024 + tid * 4];
            __syncthreads();
            float acc = 0.f;
#pragma unroll
            for (int it = 0; it < 16; ++it) {
                int j = it * 64 + tj * 4;
                f32x4 m4 = *(const f32x4*)&Ml[sc * ML_PITCH + j];
                f32x4 h4 = *(const f32x4*)&hB[j];
                acc += m4[0]*h4[0] + m4[1]*h4[1] + m4[2]*h4[2] + m4[3]*h4[3];
            }
            acc += __shfl_xor(acc, 1);
            acc += __shfl_xor(acc, 2);
            acc += __shfl_xor(acc, 4);
            acc += __shfl_xor(acc, 8);
            int sg = s0 + sc;
            if (tj == 0) scb[sc] = (sg < vlen) ? acc : -1e30f;
            __syncthreads();
            float mc = -1e30f;
#pragma unroll
            for (int s = 0; s < 16; ++s) mc = fmaxf(mc, scb[s]);
            if (tid < 16) {
                float sv = scb[tid];
                pb[tid] = (sv > -1e29f) ? expf(sv - mc) : 0.f;
            }
            __syncthreads();
            float psum = 0.f;
#pragma unroll
            for (int s = 0; s < 16; ++s) psum += pb[s];
            f32x4 ca = {0.f, 0.f, 0.f, 0.f};
#pragma unroll
            for (int s = 0; s < 16; ++s) {
                float p = pb[s];
                short4v e4 = *(const short4v*)(&El[s * EL_PITCH + tid * 4]);
                ca[0] += p * bf2f((u16)e4[0]);
                ca[1] += p * bf2f((u16)e4[1]);
                ca[2] += p * bf2f((u16)e4[2]);
                ca[3] += p * bf2f((u16)e4[3]);
            }
            *(f32x4*)&pCtx[(size_t)wr * (32 * 8 * 1024) + (size_t)(b_at * 8 + ch) * 1024 + tid * 4] = ca;
            if (tid == 0) { pMx[(size_t)wr * 256 + b_at * 8 + ch] = mc; pSm[(size_t)wr * 256 + b_at * 8 + ch] = psum; }
        }
        grid_bar(slots, gen, (u32)(t + 1), bid, tid);
    }

    // post-loop: last combine + final h/c outputs (fp32)
    combine_slice(b_at, ch, 62, tid, 0, pCtx, pMx, pSm, ctxA);
    if (bid >= 32 && bid < 64) {
        int b = bid - 32, j = tid * 4;
#pragma unroll
        for (int i = 0; i < 4; ++i)
            out[2064384 + b * 1024 + j + i] = hF[(size_t)1 * (32 * 1024) + b * 1024 + j + i];
    } else if (bid >= 64 && bid < 96) {
        int b = bid - 64, j = tid * 4;
#pragma unroll
        for (int i = 0; i < 4; ++i)
            out[2064384 + 32768 + b * 1024 + j + i] = cF[b * 1024 + j + i];
    }
}

// ---------------------------------------------------------------------------
// k_out: dec_out[b][t][n] = tanh( [ctx | h] @ W_attn_out^T ), K = 2048 (fp32 out)
// ---------------------------------------------------------------------------
__global__ void __launch_bounds__(256)
k_out(const u16* __restrict__ ctxA, const u16* __restrict__ hAll,
      const u16* __restrict__ Wao16, float* __restrict__ out)
{
    const int bid = blockIdx.x, tid = threadIdx.x;
    const int mt = bid & 31, nt = bid >> 5;
    const int wv = tid >> 6, l = tid & 63, lr = l & 15, lq = l >> 4;
    const int r0 = mt * 64 + wv * 16;
    const int n0 = nt * 64;
    int r = r0 + lr;
    int rc = (r < 2016) ? r : 2015;
    const u16* arc = ctxA + (size_t)rc * 1024;
    const u16* arh = hAll + (size_t)rc * 1024;
    const u16* brow = Wao16 + (size_t)(n0 + lr) * 2048;
    f32x4 acc[4] = {{0,0,0,0},{0,0,0,0},{0,0,0,0},{0,0,0,0}};
    for (int k0 = 0; k0 < 2048; k0 += 32) {
        int ko = k0 + lq * 8;
        short8 av = (k0 < 1024) ? *(const short8*)(arc + ko)
                                : *(const short8*)(arh + (ko - 1024));
#pragma unroll
        for (int nf = 0; nf < 4; ++nf) {
            short8 bv = *(const short8*)(brow + (size_t)nf * 16 * 2048 + ko);
            acc[nf] = __builtin_amdgcn_mfma_f32_16x16x32_bf16(av, bv, acc[nf], 0, 0, 0);
        }
    }
#pragma unroll
    for (int nf = 0; nf < 4; ++nf) {
        int n = n0 + nf * 16 + lr;
#pragma unroll
        for (int q = 0; q < 4; ++q) {
            int rr = r0 + lq * 4 + q;
            if (rr < 2016) {
                int t = rr >> 5, b = rr & 31;
                out[(size_t)b * 64512 + t * 1024 + n] = tanhf(acc[nf][q]);
            }
        }
    }
}

// ---------------------------------------------------------------------------
extern "C" void kernel_launch(void* const* d_in, const int* in_sizes, int n_in,
                              void* d_out, int out_size, void* d_ws, size_t ws_size,
                              hipStream_t stream)
{
    (void)in_sizes; (void)n_in; (void)out_size; (void)ws_size;
    const int*   tgt  = (const int*)d_in[0];
    const float* h0   = (const float*)d_in[1];
    const float* c0   = (const float*)d_in[2];
    const float* enc  = (const float*)d_in[3];
    const int*   slen = (const int*)d_in[4];
    const float* emb  = (const float*)d_in[5];
    const float* Wih  = (const float*)d_in[6];
    const float* Whh  = (const float*)d_in[7];
    const float* bih  = (const float*)d_in[8];
    const float* bhh  = (const float*)d_in[9];
    const float* Wai  = (const float*)d_in[10];
    const float* Wao  = (const float*)d_in[11];
    float* out = (float*)d_out;

    char* ws = (char*)d_ws;
    size_t off = 0;
    auto alloc = [&](size_t bytes) -> char* {
        char* p = ws + off; off += (bytes + 255) & ~(size_t)255; return p;
    };
    u16*   xg    = (u16*)  alloc(63UL * 32 * 4096 * 2);
    float* Mf    = (float*)alloc(4096UL * 1024 * 4);
    u16*   WT    = (u16*)  alloc(1024UL * 1024 * 2);
    u16*   Wih16 = (u16*)  alloc(4096UL * 1024 * 2);
    u16*   Wao16 = (u16*)  alloc(1024UL * 2048 * 2);
    u16*   ctxA  = (u16*)  alloc(2016UL * 1024 * 2);
    u16*   hAll  = (u16*)  alloc(2016UL * 1024 * 2);
    u16*   hb    = (u16*)  alloc(2UL * 32 * 1024 * 2);
    float* hF    = (float*)alloc(2UL * 32 * 1024 * 4);
    float* cF    = (float*)alloc(32UL * 1024 * 4);
    float* pCtx  = (float*)alloc(2UL * 32 * 8 * 1024 * 4);
    float* pMx   = (float*)alloc(2UL * 32 * 8 * 4);
    float* pSm   = (float*)alloc(2UL * 32 * 8 * 4);
    u32*   bar   = (u32*)  alloc(2048);

    static int lds_set = 0;
    if (!lds_set) {
        (void)hipFuncSetAttribute((const void*)k_loop,
                                  hipFuncAttributeMaxDynamicSharedMemorySize, DYN_BYTES);
        lds_set = 1;
    }

    hipMemsetAsync(bar, 0, 2048, stream);
    hipLaunchKernelGGL(k_cvt, dim3(4096), dim3(256), 0, stream, Wih, Wih16, 4096 * 1024);
    hipLaunchKernelGGL(k_cvt, dim3(2048), dim3(256), 0, stream, Wao, Wao16, 1024 * 2048);
    hipLaunchKernelGGL(k_init, dim3(288), dim3(256), 0, stream, Wai, h0, c0, WT, cF, hb);
    hipLaunchKernelGGL(k_xg, dim3(2048), dim3(256), 0, stream, tgt, emb, Wih16, bih, bhh, xg);
    hipLaunchKernelGGL(k_M, dim3(1024), dim3(256), 0, stream, enc, WT, Mf);

    void* kargs[] = { (void*)&xg, (void*)&Mf, (void*)&ctxA, (void*)&hAll, (void*)&hb,
                      (void*)&hF, (void*)&cF, (void*)&pCtx, (void*)&pMx, (void*)&pSm,
                      (void*)&enc, (void*)&Whh, (void*)&slen, (void*)&out, (void*)&bar };
    hipLaunchCooperativeKernel((const void*)k_loop, dim3(256), dim3(256), kargs, DYN_BYTES, stream);

    hipLaunchKernelGGL(k_out, dim3(512), dim3(256), 0, stream, ctxA, hAll, Wao16, out);
}

// Round 5
// 1138.980 us; speedup vs baseline: 2.6251x; 1.2696x over previous
//
#include <hip/hip_runtime.h>

typedef __attribute__((ext_vector_type(4))) float f32x4;
typedef __attribute__((ext_vector_type(8))) short short8;
typedef __attribute__((ext_vector_type(4))) short short4v;
typedef unsigned short u16;
typedef unsigned int u32;
typedef unsigned long long u64;

#define DEV static __device__ __forceinline__

DEV float bf2f(u16 u){ union { unsigned int i; float f; } v; v.i = ((unsigned int)u) << 16; return v.f; }
DEV u16 f2bf(float f){ union { float f; unsigned int i; } v; v.f = f; unsigned int r = v.i + 0x7fffu + ((v.i >> 16) & 1u); return (u16)(r >> 16); }
DEV float sigm(float x){ return 1.f / (1.f + expf(-x)); }

// write-through (agent-coherent) stores: complete at coherence point, no wbl2 needed
DEV void stg_f32(float* p, float v){ __hip_atomic_store(p, v, __ATOMIC_RELAXED, __HIP_MEMORY_SCOPE_AGENT); }
DEV void stg_u16(u16* p, u16 v){ __hip_atomic_store(p, v, __ATOMIC_RELAXED, __HIP_MEMORY_SCOPE_AGENT); }
DEV void stg_u64(u64* p, u64 v){ __hip_atomic_store(p, v, __ATOMIC_RELAXED, __HIP_MEMORY_SCOPE_AGENT); }

DEV short8 cvt8(const float* __restrict__ p){
    const f32x4* q = (const f32x4*)p;
    f32x4 lo = q[0], hi = q[1];
    short8 r;
    r[0]=(short)f2bf(lo[0]); r[1]=(short)f2bf(lo[1]); r[2]=(short)f2bf(lo[2]); r[3]=(short)f2bf(lo[3]);
    r[4]=(short)f2bf(hi[0]); r[5]=(short)f2bf(hi[1]); r[6]=(short)f2bf(hi[2]); r[7]=(short)f2bf(hi[3]);
    return r;
}

// ---------------------------------------------------------------------------
// Distributed grid barrier. arrive: drain own stores, post slot. wait: wave 0
// polls all 256 slots (4/lane, sc1 loads), tid0 does one acquire (L2 inv).
// ---------------------------------------------------------------------------
DEV void bar_arrive(u32* __restrict__ slots, u32 n, int bid, int tid)
{
    asm volatile("s_waitcnt vmcnt(0)" ::: "memory");  // every wave drains its WT stores
    __syncthreads();
    if (tid == 0)
        __hip_atomic_store(&slots[bid], n, __ATOMIC_RELAXED, __HIP_MEMORY_SCOPE_AGENT);
}

DEV void bar_wait(u32* __restrict__ slots, u32 n, int tid)
{
    if (tid < 64) {
        for (;;) {
            u32 v0 = __hip_atomic_load(&slots[tid*4+0], __ATOMIC_RELAXED, __HIP_MEMORY_SCOPE_AGENT);
            u32 v1 = __hip_atomic_load(&slots[tid*4+1], __ATOMIC_RELAXED, __HIP_MEMORY_SCOPE_AGENT);
            u32 v2 = __hip_atomic_load(&slots[tid*4+2], __ATOMIC_RELAXED, __HIP_MEMORY_SCOPE_AGENT);
            u32 v3 = __hip_atomic_load(&slots[tid*4+3], __ATOMIC_RELAXED, __HIP_MEMORY_SCOPE_AGENT);
            bool ok = (v0 >= n) && (v1 >= n) && (v2 >= n) && (v3 >= n);
            if (__all(ok)) break;
            __builtin_amdgcn_s_sleep(2);
        }
    }
    if (tid == 0)
        (void)__hip_atomic_load(&slots[0], __ATOMIC_ACQUIRE, __HIP_MEMORY_SCOPE_AGENT); // L1/L2 inv
    __syncthreads();
}

// ---------------------------------------------------------------------------
__global__ void __launch_bounds__(256)
k_cvt(const float* __restrict__ src, u16* __restrict__ dst, int n)
{
    int i = (blockIdx.x * 256 + threadIdx.x) * 4;
    if (i + 3 < n) {
        f32x4 v = *(const f32x4*)(src + i);
        short4v o;
        o[0]=(short)f2bf(v[0]); o[1]=(short)f2bf(v[1]);
        o[2]=(short)f2bf(v[2]); o[3]=(short)f2bf(v[3]);
        *(short4v*)(dst + i) = o;
    }
}

// ---------------------------------------------------------------------------
__global__ void __launch_bounds__(256)
k_init(const float* __restrict__ Wai, const float* __restrict__ h0, const float* __restrict__ c0,
       u16* __restrict__ WT, float* __restrict__ cF, u16* __restrict__ hb)
{
    const int bid = blockIdx.x, tid = threadIdx.x;
    __shared__ u16 tl[64][65];
    if (bid < 256) {
        int ti = bid >> 4, tj = bid & 15;
        int rr = tid >> 2, cc = (tid & 3) * 16;
        for (int i = 0; i < 16; ++i)
            tl[rr][cc + i] = f2bf(Wai[(size_t)(ti * 64 + rr) * 1024 + tj * 64 + cc + i]);
        __syncthreads();
        for (int i = 0; i < 16; ++i)
            WT[(size_t)(tj * 64 + rr) * 1024 + ti * 64 + cc + i] = tl[cc + i][rr];
    } else if (bid < 288) {
        int b = bid - 256;
        int j = tid * 4;
        for (int i = 0; i < 4; ++i) {
            int k = j + i;
            float hv = (k < 512) ? h0[(size_t)b * 512 + k] : h0[(size_t)(32 + b) * 512 + (k - 512)];
            float cv = (k < 512) ? c0[(size_t)b * 512 + k] : c0[(size_t)(32 + b) * 512 + (k - 512)];
            cF[b * 1024 + k] = cv;
            hb[b * 1024 + k] = f2bf(hv);   // buffer 0 = h_0
        }
    }
}

// ---------------------------------------------------------------------------
__global__ void __launch_bounds__(256)
k_xg(const int* __restrict__ tgt, const float* __restrict__ emb,
     const u16* __restrict__ Wih16, const float* __restrict__ bih, const float* __restrict__ bhh,
     u16* __restrict__ xg)
{
    const int bid = blockIdx.x, tid = threadIdx.x;
    const int mt = bid & 31, nt = bid >> 5;
    const int wv = tid >> 6, l = tid & 63, lr = l & 15, lq = l >> 4;
    const int r0 = mt * 64 + wv * 16;
    const int n0 = nt * 64;
    int r = r0 + lr;
    int rc = (r < 2016) ? r : 2015;
    int t = rc >> 5, b = rc & 31;
    const float* arow = emb + (size_t)tgt[b * 64 + t] * 1024;
    const u16* brow = Wih16 + (size_t)(n0 + lr) * 1024;
    f32x4 acc[4] = {{0,0,0,0},{0,0,0,0},{0,0,0,0},{0,0,0,0}};
    for (int k0 = 0; k0 < 1024; k0 += 32) {
        int ko = k0 + lq * 8;
        short8 av = cvt8(arow + ko);
#pragma unroll
        for (int nf = 0; nf < 4; ++nf) {
            short8 bv = *(const short8*)(brow + (size_t)nf * 16 * 1024 + ko);
            acc[nf] = __builtin_amdgcn_mfma_f32_16x16x32_bf16(av, bv, acc[nf], 0, 0, 0);
        }
    }
#pragma unroll
    for (int nf = 0; nf < 4; ++nf) {
        int n = n0 + nf * 16 + lr;
        float bias = bih[n] + bhh[n];
#pragma unroll
        for (int q = 0; q < 4; ++q) {
            int rr = r0 + lq * 4 + q;
            if (rr < 2016) xg[(size_t)rr * 4096 + n] = f2bf(acc[nf][q] + bias);
        }
    }
}

// ---------------------------------------------------------------------------
__global__ void __launch_bounds__(256)
k_M(const float* __restrict__ enc, const u16* __restrict__ WT, float* __restrict__ Mf)
{
    const int bid = blockIdx.x, tid = threadIdx.x;
    const int mt = bid & 63, nt = bid >> 6;
    const int wv = tid >> 6, l = tid & 63, lr = l & 15, lq = l >> 4;
    const int r0 = mt * 64 + wv * 16;
    const int n0 = nt * 64;
    const float* arow = enc + (size_t)(r0 + lr) * 1024;
    const u16* brow = WT + (size_t)(n0 + lr) * 1024;
    f32x4 acc[4] = {{0,0,0,0},{0,0,0,0},{0,0,0,0},{0,0,0,0}};
    for (int k0 = 0; k0 < 1024; k0 += 32) {
        int ko = k0 + lq * 8;
        short8 av = cvt8(arow + ko);
#pragma unroll
        for (int nf = 0; nf < 4; ++nf) {
            short8 bv = *(const short8*)(brow + (size_t)nf * 16 * 1024 + ko);
            acc[nf] = __builtin_amdgcn_mfma_f32_16x16x32_bf16(av, bv, acc[nf], 0, 0, 0);
        }
    }
#pragma unroll
    for (int nf = 0; nf < 4; ++nf) {
        int n = n0 + nf * 16 + lr;
#pragma unroll
        for (int q = 0; q < 4; ++q)
            Mf[(size_t)(r0 + lq * 4 + q) * 1024 + n] = acc[nf][q];
    }
}

// ---------------------------------------------------------------------------
DEV void combine_slice(int b, int ch, int tstore, int tid, int pidx,
                       const float* __restrict__ pCtx, const float* __restrict__ pMx,
                       const float* __restrict__ pSm, u16* __restrict__ ctxA)
{
    if (tid >= 32) return;
    const float* mx = pMx + (size_t)pidx * 256 + b * 8;
    const float* sm = pSm + (size_t)pidx * 256 + b * 8;
    const float* pc = pCtx + (size_t)pidx * (32 * 8 * 1024) + (size_t)b * 8 * 1024;
    float gm = -1e30f;
#pragma unroll
    for (int c = 0; c < 8; ++c) gm = fmaxf(gm, mx[c]);
    float wsum = 0.f, e[8];
#pragma unroll
    for (int c = 0; c < 8; ++c) { e[c] = expf(mx[c] - gm); wsum += sm[c] * e[c]; }
    float inv = 1.f / wsum;
    int j = ch * 128 + tid * 4;
    f32x4 a = {0.f, 0.f, 0.f, 0.f};
#pragma unroll
    for (int c = 0; c < 8; ++c) {
        f32x4 v = *(const f32x4*)(pc + (size_t)c * 1024 + j);
        float s = e[c] * inv;
        a[0] += v[0] * s; a[1] += v[1] * s; a[2] += v[2] * s; a[3] += v[3] * s;
    }
    short4v o4;
    o4[0] = (short)f2bf(a[0]); o4[1] = (short)f2bf(a[1]);
    o4[2] = (short)f2bf(a[2]); o4[3] = (short)f2bf(a[3]);
    *(short4v*)(ctxA + ((size_t)tstore * 32 + b) * 1024 + j) = o4;
}

// ---------------------------------------------------------------------------
// k_loop: persistent cooperative kernel, write-through shared state +
// distributed slot barrier. c-state lives in registers (tid>=128).
// ---------------------------------------------------------------------------
#define WL_PITCH 1032
#define ML_PITCH 1028
#define EL_PITCH 1032
#define WL_BYTES (16 * WL_PITCH * 2)
#define ML_BYTES (16 * ML_PITCH * 4)
#define EL_BYTES (16 * EL_PITCH * 2)
#define DYN_BYTES (WL_BYTES + ML_BYTES + EL_BYTES)

__global__ void __launch_bounds__(256, 1)
k_loop(const u16* __restrict__ xg, const float* __restrict__ Mf,
       u16* __restrict__ ctxA, u16* __restrict__ hAll,
       u16* __restrict__ hb, float* __restrict__ hF, float* __restrict__ cF,
       float* __restrict__ pCtx, float* __restrict__ pMx, float* __restrict__ pSm,
       const float* __restrict__ enc, const float* __restrict__ Whh,
       const int* __restrict__ slen, float* __restrict__ out, u32* __restrict__ bar)
{
    const int bid = blockIdx.x, tid = threadIdx.x;
    const int wv = tid >> 6, l = tid & 63, lr = l & 15, lq = l >> 4;
    u32* slots = bar;

    extern __shared__ char smem[];
    u16*   Wl = (u16*)smem;                         // [16][WL_PITCH]
    float* Ml = (float*)(smem + WL_BYTES);          // [16][ML_PITCH]
    u16*   El = (u16*)(smem + WL_BYTES + ML_BYTES); // [16][EL_PITCH]

    __shared__ float red[4][32][16];
    __shared__ float hB[1024];
    __shared__ float scb[16], pb[16];

    const int b_at = bid >> 3, ch = bid & 7, s0 = ch * 16;
    const int sc = tid >> 4, tj = tid & 15;

    // ---- prologue: LDS-resident data ----
    {   // W_hh: row n = gate (n>>2), hidden col bid*4 + (n&3)
        int n = tid >> 4;
        int cc = (tid & 15) * 64;
        const float* src = Whh + ((size_t)((n >> 2) * 1024 + bid * 4 + (n & 3))) * 1024 + cc;
        u16* dst = &Wl[n * WL_PITCH + cc];
#pragma unroll
        for (int i = 0; i < 8; ++i)
            *(short8*)(dst + i * 8) = cvt8(src + i * 8);
    }
    {   // M slice rows [b_at*128+s0 .. +16), fp32
        int row = tid >> 4;
        const float* src = Mf + (size_t)(b_at * 128 + s0 + row) * 1024;
        float* dst = &Ml[row * ML_PITCH];
#pragma unroll
        for (int i = 0; i < 16; ++i) {
            int c = (tid & 15) * 4 + i * 64;
            *(f32x4*)(dst + c) = *(const f32x4*)(src + c);
        }
    }
    {   // enc slice rows (same), bf16
        int row = tid >> 4;
        const float* src = enc + (size_t)(b_at * 128 + s0 + row) * 1024;
        u16* dst = &El[row * EL_PITCH];
#pragma unroll
        for (int i = 0; i < 16; ++i) {
            int c = (tid & 15) * 4 + i * 64;
            f32x4 v = *(const f32x4*)(src + c);
            short4v o;
            o[0]=(short)f2bf(v[0]); o[1]=(short)f2bf(v[1]);
            o[2]=(short)f2bf(v[2]); o[3]=(short)f2bf(v[3]);
            *(short4v*)(dst + c) = o;
        }
    }

    // LSTM thread-locals (tid in [128,256)): b = tid&31, kk = (tid>>5)-4
    const int lb = tid & 31, lkk = (tid >> 5) - 4;
    const int lkidx = bid * 4 + lkk;
    float creg = 0.f;
    float xgv[4] = {0,0,0,0}, xgn[4] = {0,0,0,0};
    if (tid >= 128) {
        creg = cF[lb * 1024 + lkidx];
#pragma unroll
        for (int g = 0; g < 4; ++g)
            xgv[g] = bf2f(xg[((size_t)lb) * 4096 + g * 1024 + lkidx]);   // t = 0
    }
    __syncthreads();

    int vlen = slen[b_at]; if (vlen < 1) vlen = 1;

    for (int t = 0; t < 64; ++t) {
        const int rd = t & 1, wr = rd ^ 1;

        if (t >= 1) {
            // ---- attention partials for step t-1 (h_t = hF[rd]) ----
            *(f32x4*)&hB[tid * 4] = *(const f32x4*)&hF[(size_t)rd * (32 * 1024) + b_at * 1024 + tid * 4];
            __syncthreads();
            float acc = 0.f;
#pragma unroll
            for (int it = 0; it < 16; ++it) {
                int j = it * 64 + tj * 4;
                f32x4 m4 = *(const f32x4*)&Ml[sc * ML_PITCH + j];
                f32x4 h4 = *(const f32x4*)&hB[j];
                acc += m4[0]*h4[0] + m4[1]*h4[1] + m4[2]*h4[2] + m4[3]*h4[3];
            }
            acc += __shfl_xor(acc, 1);
            acc += __shfl_xor(acc, 2);
            acc += __shfl_xor(acc, 4);
            acc += __shfl_xor(acc, 8);
            int sg = s0 + sc;
            if (tj == 0) scb[sc] = (sg < vlen) ? acc : -1e30f;
            __syncthreads();
            float mc = -1e30f;
#pragma unroll
            for (int s = 0; s < 16; ++s) mc = fmaxf(mc, scb[s]);
            if (tid < 16) {
                float sv = scb[tid];
                pb[tid] = (sv > -1e29f) ? expf(sv - mc) : 0.f;
            }
            __syncthreads();
            float psum = 0.f;
#pragma unroll
            for (int s = 0; s < 16; ++s) psum += pb[s];
            f32x4 ca = {0.f, 0.f, 0.f, 0.f};
#pragma unroll
            for (int s = 0; s < 16; ++s) {
                float p = pb[s];
                short4v e4 = *(const short4v*)(&El[s * EL_PITCH + tid * 4]);
                ca[0] += p * bf2f((u16)e4[0]);
                ca[1] += p * bf2f((u16)e4[1]);
                ca[2] += p * bf2f((u16)e4[2]);
                ca[3] += p * bf2f((u16)e4[3]);
            }
            union { f32x4 v; u64 q[2]; } cu; cu.v = ca;
            u64* pdst = (u64*)&pCtx[(size_t)wr * (32 * 8 * 1024) + (size_t)(b_at * 8 + ch) * 1024 + tid * 4];
            stg_u64(pdst, cu.q[0]);
            stg_u64(pdst + 1, cu.q[1]);
            if (tid == 0) {
                stg_f32(&pMx[(size_t)wr * 256 + b_at * 8 + ch], mc);
                stg_f32(&pSm[(size_t)wr * 256 + b_at * 8 + ch], psum);
            }
        }

        if (t < 63) {
            // ---- gates GEMM: this block's 16 gate-columns ----
            const u16* hrd = hb + (size_t)rd * (32 * 1024);
            f32x4 acc0 = {0,0,0,0}, acc1 = {0,0,0,0};
            const int kb = wv * 256;
#pragma unroll
            for (int ks = 0; ks < 8; ++ks) {
                int ko = kb + ks * 32 + lq * 8;
                short8 a0 = *(const short8*)(hrd + lr * 1024 + ko);
                short8 a1 = *(const short8*)(hrd + (16 + lr) * 1024 + ko);
                short8 bv = *(const short8*)(&Wl[lr * WL_PITCH + ko]);
                acc0 = __builtin_amdgcn_mfma_f32_16x16x32_bf16(a0, bv, acc0, 0, 0, 0);
                acc1 = __builtin_amdgcn_mfma_f32_16x16x32_bf16(a1, bv, acc1, 0, 0, 0);
            }
#pragma unroll
            for (int q = 0; q < 4; ++q) {
                red[wv][lq * 4 + q][lr] = acc0[q];
                red[wv][16 + lq * 4 + q][lr] = acc1[q];
            }
        }
        __syncthreads();

        // LSTM (tid>=128) runs concurrently with combine (tid<32)
        if (t < 63 && tid >= 128) {
            float G[4];
#pragma unroll
            for (int g = 0; g < 4; ++g) {
                int n = g * 4 + lkk;
                G[g] = red[0][lb][n] + red[1][lb][n] + red[2][lb][n] + red[3][lb][n] + xgv[g];
            }
            float iS = sigm(G[0]), fS = sigm(G[1]), gT = tanhf(G[2]), oS = sigm(G[3]);
            float cn = fS * creg + iS * gT;
            float hn = oS * tanhf(cn);
            creg = cn;
            u16 h16 = f2bf(hn);
            stg_f32(&hF[(size_t)wr * (32 * 1024) + lb * 1024 + lkidx], hn);
            stg_u16(&hb[(size_t)wr * (32 * 1024) + lb * 1024 + lkidx], h16);
            hAll[((size_t)t * 32 + lb) * 1024 + lkidx] = h16;
        }
        if (t >= 2 && tid < 32)
            combine_slice(b_at, ch, t - 2, tid, rd, pCtx, pMx, pSm, ctxA);

        bar_arrive(slots, (u32)(t + 1), bid, tid);

        // overlap with barrier propagation: prefetch next step's xg
        if (t < 62 && tid >= 128) {
#pragma unroll
            for (int g = 0; g < 4; ++g)
                xgn[g] = bf2f(xg[((size_t)(t + 1) * 32 + lb) * 4096 + g * 1024 + lkidx]);
        }
        bar_wait(slots, (u32)(t + 1), tid);
        if (tid >= 128) {
#pragma unroll
            for (int g = 0; g < 4; ++g) xgv[g] = xgn[g];
        }
    }

    // post-loop: last combine + final h/c outputs (fp32)
    combine_slice(b_at, ch, 62, tid, 0, pCtx, pMx, pSm, ctxA);
    if (bid >= 32 && bid < 64) {
        int b = bid - 32, j = tid * 4;
#pragma unroll
        for (int i = 0; i < 4; ++i)
            out[2064384 + b * 1024 + j + i] = hF[(size_t)1 * (32 * 1024) + b * 1024 + j + i];
    }
    if (tid >= 128)
        out[2064384 + 32768 + lb * 1024 + lkidx] = creg;
}

// ---------------------------------------------------------------------------
__global__ void __launch_bounds__(256)
k_out(const u16* __restrict__ ctxA, const u16* __restrict__ hAll,
      const u16* __restrict__ Wao16, float* __restrict__ out)
{
    const int bid = blockIdx.x, tid = threadIdx.x;
    const int mt = bid & 31, nt = bid >> 5;
    const int wv = tid >> 6, l = tid & 63, lr = l & 15, lq = l >> 4;
    const int r0 = mt * 64 + wv * 16;
    const int n0 = nt * 64;
    int r = r0 + lr;
    int rc = (r < 2016) ? r : 2015;
    const u16* arc = ctxA + (size_t)rc * 1024;
    const u16* arh = hAll + (size_t)rc * 1024;
    const u16* brow = Wao16 + (size_t)(n0 + lr) * 2048;
    f32x4 acc[4] = {{0,0,0,0},{0,0,0,0},{0,0,0,0},{0,0,0,0}};
    for (int k0 = 0; k0 < 2048; k0 += 32) {
        int ko = k0 + lq * 8;
        short8 av = (k0 < 1024) ? *(const short8*)(arc + ko)
                                : *(const short8*)(arh + (ko - 1024));
#pragma unroll
        for (int nf = 0; nf < 4; ++nf) {
            short8 bv = *(const short8*)(brow + (size_t)nf * 16 * 2048 + ko);
            acc[nf] = __builtin_amdgcn_mfma_f32_16x16x32_bf16(av, bv, acc[nf], 0, 0, 0);
        }
    }
#pragma unroll
    for (int nf = 0; nf < 4; ++nf) {
        int n = n0 + nf * 16 + lr;
#pragma unroll
        for (int q = 0; q < 4; ++q) {
            int rr = r0 + lq * 4 + q;
            if (rr < 2016) {
                int t = rr >> 5, b = rr & 31;
                out[(size_t)b * 64512 + t * 1024 + n] = tanhf(acc[nf][q]);
            }
        }
    }
}

// ---------------------------------------------------------------------------
extern "C" void kernel_launch(void* const* d_in, const int* in_sizes, int n_in,
                              void* d_out, int out_size, void* d_ws, size_t ws_size,
                              hipStream_t stream)
{
    (void)in_sizes; (void)n_in; (void)out_size; (void)ws_size;
    const int*   tgt  = (const int*)d_in[0];
    const float* h0   = (const float*)d_in[1];
    const float* c0   = (const float*)d_in[2];
    const float* enc  = (const float*)d_in[3];
    const int*   slen = (const int*)d_in[4];
    const float* emb  = (const float*)d_in[5];
    const float* Wih  = (const float*)d_in[6];
    const float* Whh  = (const float*)d_in[7];
    const float* bih  = (const float*)d_in[8];
    const float* bhh  = (const float*)d_in[9];
    const float* Wai  = (const float*)d_in[10];
    const float* Wao  = (const float*)d_in[11];
    float* out = (float*)d_out;

    char* ws = (char*)d_ws;
    size_t off = 0;
    auto alloc = [&](size_t bytes) -> char* {
        char* p = ws + off; off += (bytes + 255) & ~(size_t)255; return p;
    };
    u16*   xg    = (u16*)  alloc(63UL * 32 * 4096 * 2);
    float* Mf    = (float*)alloc(4096UL * 1024 * 4);
    u16*   WT    = (u16*)  alloc(1024UL * 1024 * 2);
    u16*   Wih16 = (u16*)  alloc(4096UL * 1024 * 2);
    u16*   Wao16 = (u16*)  alloc(1024UL * 2048 * 2);
    u16*   ctxA  = (u16*)  alloc(2016UL * 1024 * 2);
    u16*   hAll  = (u16*)  alloc(2016UL * 1024 * 2);
    u16*   hb    = (u16*)  alloc(2UL * 32 * 1024 * 2);
    float* hF    = (float*)alloc(2UL * 32 * 1024 * 4);
    float* cF    = (float*)alloc(32UL * 1024 * 4);
    float* pCtx  = (float*)alloc(2UL * 32 * 8 * 1024 * 4);
    float* pMx   = (float*)alloc(2UL * 32 * 8 * 4);
    float* pSm   = (float*)alloc(2UL * 32 * 8 * 4);
    u32*   bar   = (u32*)  alloc(2048);

    static int lds_set = 0;
    if (!lds_set) {
        (void)hipFuncSetAttribute((const void*)k_loop,
                                  hipFuncAttributeMaxDynamicSharedMemorySize, DYN_BYTES);
        lds_set = 1;
    }

    hipMemsetAsync(bar, 0, 2048, stream);
    hipLaunchKernelGGL(k_cvt, dim3(4096), dim3(256), 0, stream, Wih, Wih16, 4096 * 1024);
    hipLaunchKernelGGL(k_cvt, dim3(2048), dim3(256), 0, stream, Wao, Wao16, 1024 * 2048);
    hipLaunchKernelGGL(k_init, dim3(288), dim3(256), 0, stream, Wai, h0, c0, WT, cF, hb);
    hipLaunchKernelGGL(k_xg, dim3(2048), dim3(256), 0, stream, tgt, emb, Wih16, bih, bhh, xg);
    hipLaunchKernelGGL(k_M, dim3(1024), dim3(256), 0, stream, enc, WT, Mf);

    void* kargs[] = { (void*)&xg, (void*)&Mf, (void*)&ctxA, (void*)&hAll, (void*)&hb,
                      (void*)&hF, (void*)&cF, (void*)&pCtx, (void*)&pMx, (void*)&pSm,
                      (void*)&enc, (void*)&Whh, (void*)&slen, (void*)&out, (void*)&bar };
    hipLaunchCooperativeKernel((const void*)k_loop, dim3(256), dim3(256), kargs, DYN_BYTES, stream);

    hipLaunchKernelGGL(k_out, dim3(512), dim3(256), 0, stream, ctxA, hAll, Wao16, out);
}

// Round 6
// 766.187 us; speedup vs baseline: 3.9024x; 1.4866x over previous
//
#include <hip/hip_runtime.h>

typedef __attribute__((ext_vector_type(4))) float f32x4;
typedef __attribute__((ext_vector_type(4))) int i32x4;
typedef __attribute__((ext_vector_type(8))) short short8;
typedef __attribute__((ext_vector_type(4))) short short4v;
typedef unsigned short u16;
typedef unsigned int u32;
typedef unsigned long long u64;

#define DEV static __device__ __forceinline__

DEV float bf2f(u16 u){ union { unsigned int i; float f; } v; v.i = ((unsigned int)u) << 16; return v.f; }
DEV u16 f2bf(float f){ union { float f; unsigned int i; } v; v.f = f; unsigned int r = v.i + 0x7fffu + ((v.i >> 16) & 1u); return (u16)(r >> 16); }
DEV float sigm(float x){ return 1.f / (1.f + expf(-x)); }

// write-through (agent-coherent) stores
DEV void stg_f32(float* p, float v){ __hip_atomic_store(p, v, __ATOMIC_RELAXED, __HIP_MEMORY_SCOPE_AGENT); }
DEV void stg_u16(u16* p, u16 v){ __hip_atomic_store(p, v, __ATOMIC_RELAXED, __HIP_MEMORY_SCOPE_AGENT); }
DEV void stg_u64(u64* p, u64 v){ __hip_atomic_store(p, v, __ATOMIC_RELAXED, __HIP_MEMORY_SCOPE_AGENT); }
// coherent reads (relaxed, agent scope)
DEV u64 ldg_u64(const u64* p){ return __hip_atomic_load(p, __ATOMIC_RELAXED, __HIP_MEMORY_SCOPE_AGENT); }
DEV float ldg_f32(const float* p){ return __hip_atomic_load(p, __ATOMIC_RELAXED, __HIP_MEMORY_SCOPE_AGENT); }
// cache-bypassing 16B load (issue only; caller does s_waitcnt + sched_barrier)
DEV void ldcc4i(i32x4* d, const void* p){
    asm volatile("global_load_dwordx4 %0, %1, off sc0 sc1" : "=v"(*d) : "v"(p) : "memory");
}
DEV void ldcc4f(f32x4* d, const void* p){
    asm volatile("global_load_dwordx4 %0, %1, off sc0 sc1" : "=v"(*d) : "v"(p) : "memory");
}
DEV short8 as_s8(i32x4 v){ union{ i32x4 i; short8 s; } u; u.i = v; return u.s; }

DEV short8 cvt8(const float* __restrict__ p){
    const f32x4* q = (const f32x4*)p;
    f32x4 lo = q[0], hi = q[1];
    short8 r;
    r[0]=(short)f2bf(lo[0]); r[1]=(short)f2bf(lo[1]); r[2]=(short)f2bf(lo[2]); r[3]=(short)f2bf(lo[3]);
    r[4]=(short)f2bf(hi[0]); r[5]=(short)f2bf(hi[1]); r[6]=(short)f2bf(hi[2]); r[7]=(short)f2bf(hi[3]);
    return r;
}

// ---------------------------------------------------------------------------
// Distributed grid barrier, no L2 invalidation (all shared data read sc0/sc1).
// ---------------------------------------------------------------------------
DEV void bar_arrive(u32* __restrict__ slots, u32 n, int bid, int tid)
{
    asm volatile("s_waitcnt vmcnt(0)" ::: "memory");
    __syncthreads();
    if (tid == 0)
        __hip_atomic_store(&slots[bid], n, __ATOMIC_RELAXED, __HIP_MEMORY_SCOPE_AGENT);
}

DEV void bar_wait(u32* __restrict__ slots, u32 n, int tid)
{
    if (tid < 64) {
        for (;;) {
            u32 v0 = __hip_atomic_load(&slots[tid*4+0], __ATOMIC_RELAXED, __HIP_MEMORY_SCOPE_AGENT);
            u32 v1 = __hip_atomic_load(&slots[tid*4+1], __ATOMIC_RELAXED, __HIP_MEMORY_SCOPE_AGENT);
            u32 v2 = __hip_atomic_load(&slots[tid*4+2], __ATOMIC_RELAXED, __HIP_MEMORY_SCOPE_AGENT);
            u32 v3 = __hip_atomic_load(&slots[tid*4+3], __ATOMIC_RELAXED, __HIP_MEMORY_SCOPE_AGENT);
            bool ok = (v0 >= n) && (v1 >= n) && (v2 >= n) && (v3 >= n);
            if (__all(ok)) break;
            __builtin_amdgcn_s_sleep(1);
        }
    }
    __syncthreads();
}

// ---------------------------------------------------------------------------
__global__ void __launch_bounds__(256)
k_cvt(const float* __restrict__ src, u16* __restrict__ dst, int n)
{
    int i = (blockIdx.x * 256 + threadIdx.x) * 4;
    if (i + 3 < n) {
        f32x4 v = *(const f32x4*)(src + i);
        short4v o;
        o[0]=(short)f2bf(v[0]); o[1]=(short)f2bf(v[1]);
        o[2]=(short)f2bf(v[2]); o[3]=(short)f2bf(v[3]);
        *(short4v*)(dst + i) = o;
    }
}

// ---------------------------------------------------------------------------
// k_gat: gather embedding rows -> bf16 xrow[r=t*32+b][1024]
// ---------------------------------------------------------------------------
__global__ void __launch_bounds__(256)
k_gat(const int* __restrict__ tgt, const float* __restrict__ emb, u16* __restrict__ xrow)
{
    int r = blockIdx.x;
    int t = r >> 5, b = r & 31;
    const float* src = emb + (size_t)tgt[b * 64 + t] * 1024;
    int j = threadIdx.x * 4;
    f32x4 v = *(const f32x4*)(src + j);
    short4v o;
    o[0]=(short)f2bf(v[0]); o[1]=(short)f2bf(v[1]);
    o[2]=(short)f2bf(v[2]); o[3]=(short)f2bf(v[3]);
    *(short4v*)(xrow + (size_t)r * 1024 + j) = o;
}

// ---------------------------------------------------------------------------
__global__ void __launch_bounds__(256)
k_init(const float* __restrict__ Wai, const float* __restrict__ h0, const float* __restrict__ c0,
       u16* __restrict__ WT, float* __restrict__ cF, u16* __restrict__ hb)
{
    const int bid = blockIdx.x, tid = threadIdx.x;
    __shared__ u16 tl[64][65];
    if (bid < 256) {
        int ti = bid >> 4, tj = bid & 15;
        int rr = tid >> 2, cc = (tid & 3) * 16;
        for (int i = 0; i < 16; ++i)
            tl[rr][cc + i] = f2bf(Wai[(size_t)(ti * 64 + rr) * 1024 + tj * 64 + cc + i]);
        __syncthreads();
        for (int i = 0; i < 16; ++i)
            WT[(size_t)(tj * 64 + rr) * 1024 + ti * 64 + cc + i] = tl[cc + i][rr];
    } else if (bid < 288) {
        int b = bid - 256;
        int j = tid * 4;
        for (int i = 0; i < 4; ++i) {
            int k = j + i;
            float hv = (k < 512) ? h0[(size_t)b * 512 + k] : h0[(size_t)(32 + b) * 512 + (k - 512)];
            float cv = (k < 512) ? c0[(size_t)b * 512 + k] : c0[(size_t)(32 + b) * 512 + (k - 512)];
            cF[b * 1024 + k] = cv;
            hb[b * 1024 + k] = f2bf(hv);
        }
    }
}

// ---------------------------------------------------------------------------
// k_xg: xg[r][m] = xrow[r] @ W_ih^T + b_ih + b_hh  (bf16 A and B)
// ---------------------------------------------------------------------------
__global__ void __launch_bounds__(256)
k_xg(const u16* __restrict__ xrow,
     const u16* __restrict__ Wih16, const float* __restrict__ bih, const float* __restrict__ bhh,
     u16* __restrict__ xg)
{
    const int bid = blockIdx.x, tid = threadIdx.x;
    const int mt = bid & 31, nt = bid >> 5;
    const int wv = tid >> 6, l = tid & 63, lr = l & 15, lq = l >> 4;
    const int r0 = mt * 64 + wv * 16;
    const int n0 = nt * 64;
    int r = r0 + lr;
    int rc = (r < 2016) ? r : 2015;
    const u16* arow = xrow + (size_t)rc * 1024;
    const u16* brow = Wih16 + (size_t)(n0 + lr) * 1024;
    f32x4 acc[4] = {{0,0,0,0},{0,0,0,0},{0,0,0,0},{0,0,0,0}};
    for (int k0 = 0; k0 < 1024; k0 += 32) {
        int ko = k0 + lq * 8;
        short8 av = *(const short8*)(arow + ko);
#pragma unroll
        for (int nf = 0; nf < 4; ++nf) {
            short8 bv = *(const short8*)(brow + (size_t)nf * 16 * 1024 + ko);
            acc[nf] = __builtin_amdgcn_mfma_f32_16x16x32_bf16(av, bv, acc[nf], 0, 0, 0);
        }
    }
#pragma unroll
    for (int nf = 0; nf < 4; ++nf) {
        int n = n0 + nf * 16 + lr;
        float bias = bih[n] + bhh[n];
#pragma unroll
        for (int q = 0; q < 4; ++q) {
            int rr = r0 + lq * 4 + q;
            if (rr < 2016) xg[(size_t)rr * 4096 + n] = f2bf(acc[nf][q] + bias);
        }
    }
}

// ---------------------------------------------------------------------------
// k_M: M = enc16 @ WT (bf16 A/B, fp32 out)
// ---------------------------------------------------------------------------
__global__ void __launch_bounds__(256)
k_M(const u16* __restrict__ enc16, const u16* __restrict__ WT, float* __restrict__ Mf)
{
    const int bid = blockIdx.x, tid = threadIdx.x;
    const int mt = bid & 63, nt = bid >> 6;
    const int wv = tid >> 6, l = tid & 63, lr = l & 15, lq = l >> 4;
    const int r0 = mt * 64 + wv * 16;
    const int n0 = nt * 64;
    const u16* arow = enc16 + (size_t)(r0 + lr) * 1024;
    const u16* brow = WT + (size_t)(n0 + lr) * 1024;
    f32x4 acc[4] = {{0,0,0,0},{0,0,0,0},{0,0,0,0},{0,0,0,0}};
    for (int k0 = 0; k0 < 1024; k0 += 32) {
        int ko = k0 + lq * 8;
        short8 av = *(const short8*)(arow + ko);
#pragma unroll
        for (int nf = 0; nf < 4; ++nf) {
            short8 bv = *(const short8*)(brow + (size_t)nf * 16 * 1024 + ko);
            acc[nf] = __builtin_amdgcn_mfma_f32_16x16x32_bf16(av, bv, acc[nf], 0, 0, 0);
        }
    }
#pragma unroll
    for (int nf = 0; nf < 4; ++nf) {
        int n = n0 + nf * 16 + lr;
#pragma unroll
        for (int q = 0; q < 4; ++q)
            Mf[(size_t)(r0 + lq * 4 + q) * 1024 + n] = acc[nf][q];
    }
}

// ---------------------------------------------------------------------------
// combine 16 half-chunk partials -> ctxA[tstore] (tid<32)
// ---------------------------------------------------------------------------
DEV void combine16(int b, int ch, int tstore, int tid, int slot,
                   const float* __restrict__ pCtx, const float* __restrict__ pMx,
                   const float* __restrict__ pSm, u16* __restrict__ ctxA)
{
    if (tid >= 32) return;
    const float* mx = pMx + (size_t)slot * 512 + b * 16;
    const float* sm = pSm + (size_t)slot * 512 + b * 16;
    const float* pc = pCtx + (size_t)slot * (32 * 16 * 1024) + (size_t)b * 16 * 1024;
    float m16[16], s16[16];
#pragma unroll
    for (int c = 0; c < 16; ++c) { m16[c] = ldg_f32(mx + c); s16[c] = ldg_f32(sm + c); }
    float gm = -1e30f;
#pragma unroll
    for (int c = 0; c < 16; ++c) gm = fmaxf(gm, m16[c]);
    float wsum = 0.f, e[16];
#pragma unroll
    for (int c = 0; c < 16; ++c) { e[c] = expf(m16[c] - gm); wsum += s16[c] * e[c]; }
    float inv = 1.f / wsum;
    int j = ch * 128 + tid * 4;
    f32x4 a = {0.f, 0.f, 0.f, 0.f};
#pragma unroll
    for (int c = 0; c < 16; ++c) {
        union { u64 q[2]; f32x4 v; } u;
        const u64* p = (const u64*)(pc + (size_t)c * 1024 + j);
        u.q[0] = ldg_u64(p); u.q[1] = ldg_u64(p + 1);
        float s = e[c] * inv;
        a[0] += u.v[0] * s; a[1] += u.v[1] * s; a[2] += u.v[2] * s; a[3] += u.v[3] * s;
    }
    short4v o4;
    o4[0] = (short)f2bf(a[0]); o4[1] = (short)f2bf(a[1]);
    o4[2] = (short)f2bf(a[2]); o4[3] = (short)f2bf(a[3]);
    *(short4v*)(ctxA + ((size_t)tstore * 32 + b) * 1024 + j) = o4;
}

// ---------------------------------------------------------------------------
// k_loop: wave-specialized persistent kernel.
//   waves 0-1: gates GEMM (bypass A-loads, counted vmcnt pipeline)
//   waves 2-3: attention (in-wave softmax) then LSTM
//   shadow after arrive: combine(t-2) + xg prefetch
// ---------------------------------------------------------------------------
#define WL_PITCH 1032
#define ML_PITCH 1028
#define EL_PITCH 1032
#define WL_BYTES (16 * WL_PITCH * 2)
#define ML_BYTES (16 * ML_PITCH * 4)
#define EL_BYTES (16 * EL_PITCH * 2)
#define DYN_BYTES (WL_BYTES + ML_BYTES + EL_BYTES)

__global__ void __launch_bounds__(256, 1)
k_loop(const u16* __restrict__ xg, const float* __restrict__ Mf,
       u16* __restrict__ ctxA, u16* __restrict__ hAll,
       u16* __restrict__ hb, float* __restrict__ hF, float* __restrict__ cF,
       float* __restrict__ pCtx, float* __restrict__ pMx, float* __restrict__ pSm,
       const float* __restrict__ enc, const float* __restrict__ Whh,
       const int* __restrict__ slen, float* __restrict__ out, u32* __restrict__ bar)
{
    const int bid = blockIdx.x, tid = threadIdx.x;
    const int wv = tid >> 6, l = tid & 63, lr = l & 15, lq = l >> 4;
    u32* slots = bar;

    extern __shared__ char smem[];
    u16*   Wl = (u16*)smem;                          // [16][WL_PITCH]
    float* Ml = (float*)(smem + WL_BYTES);           // [16][ML_PITCH]
    u16*   El = (u16*)(smem + WL_BYTES + ML_BYTES);  // [16][EL_PITCH]

    __shared__ float red[2][32][16];

    const int b_at = bid >> 3, ch = bid & 7, s0 = ch * 16;

    // ---- prologue ----
    {   // W_hh rows for this block's 16 gate-columns
        int n = tid >> 4;
        int cc = (tid & 15) * 64;
        const float* src = Whh + ((size_t)((n >> 2) * 1024 + bid * 4 + (n & 3))) * 1024 + cc;
        u16* dst = &Wl[n * WL_PITCH + cc];
#pragma unroll
        for (int i = 0; i < 8; ++i)
            *(short8*)(dst + i * 8) = cvt8(src + i * 8);
    }
    {   // M slice (fp32)
        int row = tid >> 4;
        const float* src = Mf + (size_t)(b_at * 128 + s0 + row) * 1024;
        float* dst = &Ml[row * ML_PITCH];
#pragma unroll
        for (int i = 0; i < 16; ++i) {
            int c = (tid & 15) * 4 + i * 64;
            *(f32x4*)(dst + c) = *(const f32x4*)(src + c);
        }
    }
    {   // enc slice (bf16)
        int row = tid >> 4;
        const float* src = enc + (size_t)(b_at * 128 + s0 + row) * 1024;
        u16* dst = &El[row * EL_PITCH];
#pragma unroll
        for (int i = 0; i < 16; ++i) {
            int c = (tid & 15) * 4 + i * 64;
            f32x4 v = *(const f32x4*)(src + c);
            short4v o;
            o[0]=(short)f2bf(v[0]); o[1]=(short)f2bf(v[1]);
            o[2]=(short)f2bf(v[2]); o[3]=(short)f2bf(v[3]);
            *(short4v*)(dst + c) = o;
        }
    }

    // LSTM locals (tid in [128,256)): batch lb, hidden col lkidx
    const int lb = tid & 31, lkk = (tid >> 5) - 4;
    const int lkidx = bid * 4 + lkk;
    float creg = 0.f;
    float xgv[4] = {0,0,0,0};
    if (tid >= 128) {
        creg = cF[lb * 1024 + lkidx];
#pragma unroll
        for (int g = 0; g < 4; ++g)
            xgv[g] = bf2f(xg[((size_t)lb) * 4096 + g * 1024 + lkidx]);   // t=0
    }
    int vlen = slen[b_at]; if (vlen < 1) vlen = 1;
    __syncthreads();

    for (int t = 0; t < 64; ++t) {
        if (t >= 1) bar_wait(slots, (u32)t, tid);

        if (t < 63 && wv < 2) {
            // ---- gates GEMM (waves 0-1, K split 2-way) ----
            const u16* hrd = hb + (size_t)(t & 1) * (32 * 1024);
            const u16* p0 = hrd + lr * 1024 + wv * 512 + lq * 8;
            const u16* p1 = p0 + 16 * 1024;
            i32x4 a0b[4], a1b[4];
            f32x4 acc0 = {0,0,0,0}, acc1 = {0,0,0,0};
            ldcc4i(&a0b[0], p0);        ldcc4i(&a1b[0], p1);
            ldcc4i(&a0b[1], p0 + 32);   ldcc4i(&a1b[1], p1 + 32);
#pragma unroll
            for (int ks = 0; ks < 16; ++ks) {
                if (ks < 14) {
                    ldcc4i(&a0b[(ks + 2) & 3], p0 + (ks + 2) * 32);
                    ldcc4i(&a1b[(ks + 2) & 3], p1 + (ks + 2) * 32);
                    asm volatile("s_waitcnt vmcnt(4)" ::: "memory");
                } else if (ks == 14) {
                    asm volatile("s_waitcnt vmcnt(2)" ::: "memory");
                } else {
                    asm volatile("s_waitcnt vmcnt(0)" ::: "memory");
                }
                __builtin_amdgcn_sched_barrier(0);
                short8 bv = *(const short8*)(&Wl[lr * WL_PITCH + wv * 512 + lq * 8 + ks * 32]);
                acc0 = __builtin_amdgcn_mfma_f32_16x16x32_bf16(as_s8(a0b[ks & 3]), bv, acc0, 0, 0, 0);
                acc1 = __builtin_amdgcn_mfma_f32_16x16x32_bf16(as_s8(a1b[ks & 3]), bv, acc1, 0, 0, 0);
            }
#pragma unroll
            for (int q = 0; q < 4; ++q) {
                red[wv][lq * 4 + q][lr] = acc0[q];
                red[wv][16 + lq * 4 + q][lr] = acc1[q];
            }
        }

        if (t >= 1 && wv >= 2) {
            // ---- attention for h_t (waves 2-3, fully in-wave) ----
            const int w = wv - 2;
            const int lane = l;
            const float* hrow = hF + (size_t)(t & 1) * (32 * 1024) + b_at * 1024;
            f32x4 hreg[4];
            ldcc4f(&hreg[0], hrow + 0 * 256 + lane * 4);
            ldcc4f(&hreg[1], hrow + 1 * 256 + lane * 4);
            ldcc4f(&hreg[2], hrow + 2 * 256 + lane * 4);
            ldcc4f(&hreg[3], hrow + 3 * 256 + lane * 4);
            asm volatile("s_waitcnt vmcnt(0)" ::: "memory");
            __builtin_amdgcn_sched_barrier(0);
            float part[8];
#pragma unroll
            for (int r = 0; r < 8; ++r) {
                const float* mrow = &Ml[(w * 8 + r) * ML_PITCH];
                float s = 0.f;
#pragma unroll
                for (int c = 0; c < 4; ++c) {
                    f32x4 m4 = *(const f32x4*)(mrow + c * 256 + lane * 4);
                    s += m4[0]*hreg[c][0] + m4[1]*hreg[c][1] + m4[2]*hreg[c][2] + m4[3]*hreg[c][3];
                }
                part[r] = s;
            }
#pragma unroll
            for (int d = 1; d < 64; d <<= 1) {
#pragma unroll
                for (int r = 0; r < 8; ++r) part[r] += __shfl_xor(part[r], d);
            }
            int sgb = s0 + w * 8;
            float mc = -1e30f;
#pragma unroll
            for (int r = 0; r < 8; ++r) {
                part[r] = (sgb + r < vlen) ? part[r] : -1e30f;
                mc = fmaxf(mc, part[r]);
            }
            float e8[8]; float psum = 0.f;
#pragma unroll
            for (int r = 0; r < 8; ++r) {
                e8[r] = (part[r] > -1e29f) ? expf(part[r] - mc) : 0.f;
                psum += e8[r];
            }
            f32x4 ca[4] = {{0,0,0,0},{0,0,0,0},{0,0,0,0},{0,0,0,0}};
#pragma unroll
            for (int r = 0; r < 8; ++r) {
                float p = e8[r];
                const u16* erow = &El[(w * 8 + r) * EL_PITCH];
#pragma unroll
                for (int c = 0; c < 4; ++c) {
                    short4v e4 = *(const short4v*)(erow + c * 256 + lane * 4);
                    ca[c][0] += p * bf2f((u16)e4[0]);
                    ca[c][1] += p * bf2f((u16)e4[1]);
                    ca[c][2] += p * bf2f((u16)e4[2]);
                    ca[c][3] += p * bf2f((u16)e4[3]);
                }
            }
            float* pd = pCtx + (size_t)(t & 3) * (32 * 16 * 1024)
                             + (size_t)(b_at * 16 + ch * 2 + w) * 1024;
#pragma unroll
            for (int c = 0; c < 4; ++c) {
                union { f32x4 v; u64 q[2]; } cu; cu.v = ca[c];
                u64* p = (u64*)(pd + c * 256 + lane * 4);
                stg_u64(p, cu.q[0]);
                stg_u64(p + 1, cu.q[1]);
            }
            if (lane == 0) {
                stg_f32(&pMx[(size_t)(t & 3) * 512 + b_at * 16 + ch * 2 + w], mc);
                stg_f32(&pSm[(size_t)(t & 3) * 512 + b_at * 16 + ch * 2 + w], psum);
            }
        }
        __syncthreads();

        if (t < 63 && tid >= 128) {
            // ---- LSTM elementwise ----
            float G[4];
#pragma unroll
            for (int g = 0; g < 4; ++g) {
                int n = g * 4 + lkk;
                G[g] = red[0][lb][n] + red[1][lb][n] + xgv[g];
            }
            float iS = sigm(G[0]), fS = sigm(G[1]), gT = tanhf(G[2]), oS = sigm(G[3]);
            float cn = fS * creg + iS * gT;
            float hn = oS * tanhf(cn);
            creg = cn;
            u16 h16 = f2bf(hn);
            int sl = (t + 1) & 1;
            stg_f32(&hF[(size_t)sl * (32 * 1024) + lb * 1024 + lkidx], hn);
            stg_u16(&hb[(size_t)sl * (32 * 1024) + lb * 1024 + lkidx], h16);
            hAll[((size_t)t * 32 + lb) * 1024 + lkidx] = h16;
        }

        bar_arrive(slots, (u32)(t + 1), bid, tid);

        // ---- shadow: combine + xg prefetch overlap barrier propagation ----
        if (t >= 2)
            combine16(b_at, ch, t - 2, tid, (t - 1) & 3, pCtx, pMx, pSm, ctxA);
        if (t < 62 && tid >= 128) {
#pragma unroll
            for (int g = 0; g < 4; ++g)
                xgv[g] = bf2f(xg[((size_t)(t + 1) * 32 + lb) * 4096 + g * 1024 + lkidx]);
        }
    }

    bar_wait(slots, 64u, tid);
    combine16(b_at, ch, 62, tid, 3, pCtx, pMx, pSm, ctxA);
    if (bid >= 32 && bid < 64) {
        int b = bid - 32, j = tid * 4;
#pragma unroll
        for (int i = 0; i < 4; ++i)
            out[2064384 + b * 1024 + j + i] = ldg_f32(&hF[(size_t)1 * (32 * 1024) + b * 1024 + j + i]);
    }
    if (tid >= 128)
        out[2064384 + 32768 + lb * 1024 + lkidx] = creg;
}

// ---------------------------------------------------------------------------
__global__ void __launch_bounds__(256)
k_out(const u16* __restrict__ ctxA, const u16* __restrict__ hAll,
      const u16* __restrict__ Wao16, float* __restrict__ out)
{
    const int bid = blockIdx.x, tid = threadIdx.x;
    const int mt = bid & 31, nt = bid >> 5;
    const int wv = tid >> 6, l = tid & 63, lr = l & 15, lq = l >> 4;
    const int r0 = mt * 64 + wv * 16;
    const int n0 = nt * 64;
    int r = r0 + lr;
    int rc = (r < 2016) ? r : 2015;
    const u16* arc = ctxA + (size_t)rc * 1024;
    const u16* arh = hAll + (size_t)rc * 1024;
    const u16* brow = Wao16 + (size_t)(n0 + lr) * 2048;
    f32x4 acc[4] = {{0,0,0,0},{0,0,0,0},{0,0,0,0},{0,0,0,0}};
    for (int k0 = 0; k0 < 2048; k0 += 32) {
        int ko = k0 + lq * 8;
        short8 av = (k0 < 1024) ? *(const short8*)(arc + ko)
                                : *(const short8*)(arh + (ko - 1024));
#pragma unroll
        for (int nf = 0; nf < 4; ++nf) {
            short8 bv = *(const short8*)(brow + (size_t)nf * 16 * 2048 + ko);
            acc[nf] = __builtin_amdgcn_mfma_f32_16x16x32_bf16(av, bv, acc[nf], 0, 0, 0);
        }
    }
#pragma unroll
    for (int nf = 0; nf < 4; ++nf) {
        int n = n0 + nf * 16 + lr;
#pragma unroll
        for (int q = 0; q < 4; ++q) {
            int rr = r0 + lq * 4 + q;
            if (rr < 2016) {
                int t = rr >> 5, b = rr & 31;
                out[(size_t)b * 64512 + t * 1024 + n] = tanhf(acc[nf][q]);
            }
        }
    }
}

// ---------------------------------------------------------------------------
extern "C" void kernel_launch(void* const* d_in, const int* in_sizes, int n_in,
                              void* d_out, int out_size, void* d_ws, size_t ws_size,
                              hipStream_t stream)
{
    (void)in_sizes; (void)n_in; (void)out_size; (void)ws_size;
    const int*   tgt  = (const int*)d_in[0];
    const float* h0   = (const float*)d_in[1];
    const float* c0   = (const float*)d_in[2];
    const float* enc  = (const float*)d_in[3];
    const int*   slen = (const int*)d_in[4];
    const float* emb  = (const float*)d_in[5];
    const float* Wih  = (const float*)d_in[6];
    const float* Whh  = (const float*)d_in[7];
    const float* bih  = (const float*)d_in[8];
    const float* bhh  = (const float*)d_in[9];
    const float* Wai  = (const float*)d_in[10];
    const float* Wao  = (const float*)d_in[11];
    float* out = (float*)d_out;

    char* ws = (char*)d_ws;
    size_t off = 0;
    auto alloc = [&](size_t bytes) -> char* {
        char* p = ws + off; off += (bytes + 255) & ~(size_t)255; return p;
    };
    u16*   xg    = (u16*)  alloc(63UL * 32 * 4096 * 2);
    float* Mf    = (float*)alloc(4096UL * 1024 * 4);
    u16*   WT    = (u16*)  alloc(1024UL * 1024 * 2);
    u16*   Wih16 = (u16*)  alloc(4096UL * 1024 * 2);
    u16*   Wao16 = (u16*)  alloc(1024UL * 2048 * 2);
    u16*   ctxA  = (u16*)  alloc(2016UL * 1024 * 2);
    u16*   hAll  = (u16*)  alloc(2016UL * 1024 * 2);
    u16*   hb    = (u16*)  alloc(2UL * 32 * 1024 * 2);
    float* hF    = (float*)alloc(2UL * 32 * 1024 * 4);
    float* cF    = (float*)alloc(32UL * 1024 * 4);
    float* pCtx  = (float*)alloc(4UL * 32 * 16 * 1024 * 4);
    float* pMx   = (float*)alloc(4UL * 512 * 4);
    float* pSm   = (float*)alloc(4UL * 512 * 4);
    u16*   xrow  = (u16*)  alloc(2016UL * 1024 * 2);
    u16*   enc16 = (u16*)  alloc(4096UL * 1024 * 2);
    u32*   bar   = (u32*)  alloc(2048);

    static int lds_set = 0;
    if (!lds_set) {
        (void)hipFuncSetAttribute((const void*)k_loop,
                                  hipFuncAttributeMaxDynamicSharedMemorySize, DYN_BYTES);
        lds_set = 1;
    }

    hipMemsetAsync(bar, 0, 2048, stream);
    hipLaunchKernelGGL(k_cvt, dim3(4096), dim3(256), 0, stream, Wih, Wih16, 4096 * 1024);
    hipLaunchKernelGGL(k_cvt, dim3(2048), dim3(256), 0, stream, Wao, Wao16, 1024 * 2048);
    hipLaunchKernelGGL(k_cvt, dim3(4096), dim3(256), 0, stream, enc, enc16, 4096 * 1024);
    hipLaunchKernelGGL(k_gat, dim3(2016), dim3(256), 0, stream, tgt, emb, xrow);
    hipLaunchKernelGGL(k_init, dim3(288), dim3(256), 0, stream, Wai, h0, c0, WT, cF, hb);
    hipLaunchKernelGGL(k_xg, dim3(2048), dim3(256), 0, stream, xrow, Wih16, bih, bhh, xg);
    hipLaunchKernelGGL(k_M, dim3(1024), dim3(256), 0, stream, enc16, WT, Mf);

    void* kargs[] = { (void*)&xg, (void*)&Mf, (void*)&ctxA, (void*)&hAll, (void*)&hb,
                      (void*)&hF, (void*)&cF, (void*)&pCtx, (void*)&pMx, (void*)&pSm,
                      (void*)&enc, (void*)&Whh, (void*)&slen, (void*)&out, (void*)&bar };
    hipLaunchCooperativeKernel((const void*)k_loop, dim3(256), dim3(256), kargs, DYN_BYTES, stream);

    hipLaunchKernelGGL(k_out, dim3(512), dim3(256), 0, stream, ctxA, hAll, Wao16, out);
}

// Round 7
// 753.386 us; speedup vs baseline: 3.9687x; 1.0170x over previous
//
#include <hip/hip_runtime.h>

typedef __attribute__((ext_vector_type(4))) float f32x4;
typedef __attribute__((ext_vector_type(4))) int i32x4;
typedef __attribute__((ext_vector_type(8))) short short8;
typedef __attribute__((ext_vector_type(4))) short short4v;
typedef unsigned short u16;
typedef unsigned int u32;
typedef unsigned long long u64;

#define DEV static __device__ __forceinline__

DEV float bf2f(u16 u){ union { unsigned int i; float f; } v; v.i = ((unsigned int)u) << 16; return v.f; }
DEV u16 f2bf(float f){ union { float f; unsigned int i; } v; v.f = f; unsigned int r = v.i + 0x7fffu + ((v.i >> 16) & 1u); return (u16)(r >> 16); }
DEV float sigm(float x){ return 1.f / (1.f + expf(-x)); }

// write-through (agent-coherent) stores
DEV void stg_f32(float* p, float v){ __hip_atomic_store(p, v, __ATOMIC_RELAXED, __HIP_MEMORY_SCOPE_AGENT); }
DEV void stg_u16(u16* p, u16 v){ __hip_atomic_store(p, v, __ATOMIC_RELAXED, __HIP_MEMORY_SCOPE_AGENT); }
DEV void stg_u64(u64* p, u64 v){ __hip_atomic_store(p, v, __ATOMIC_RELAXED, __HIP_MEMORY_SCOPE_AGENT); }
// coherent reads (relaxed, agent scope)
DEV u64 ldg_u64(const u64* p){ return __hip_atomic_load(p, __ATOMIC_RELAXED, __HIP_MEMORY_SCOPE_AGENT); }
DEV float ldg_f32(const float* p){ return __hip_atomic_load(p, __ATOMIC_RELAXED, __HIP_MEMORY_SCOPE_AGENT); }
// cache-bypassing 16B load (issue only; caller does s_waitcnt + sched_barrier)
DEV void ldcc4i(i32x4* d, const void* p){
    asm volatile("global_load_dwordx4 %0, %1, off sc0 sc1" : "=v"(*d) : "v"(p) : "memory");
}
DEV void ldcc4f(f32x4* d, const void* p){
    asm volatile("global_load_dwordx4 %0, %1, off sc0 sc1" : "=v"(*d) : "v"(p) : "memory");
}
DEV short8 as_s8(i32x4 v){ union{ i32x4 i; short8 s; } u; u.i = v; return u.s; }

DEV short8 cvt8(const float* __restrict__ p){
    const f32x4* q = (const f32x4*)p;
    f32x4 lo = q[0], hi = q[1];
    short8 r;
    r[0]=(short)f2bf(lo[0]); r[1]=(short)f2bf(lo[1]); r[2]=(short)f2bf(lo[2]); r[3]=(short)f2bf(lo[3]);
    r[4]=(short)f2bf(hi[0]); r[5]=(short)f2bf(hi[1]); r[6]=(short)f2bf(hi[2]); r[7]=(short)f2bf(hi[3]);
    return r;
}

// ---------------------------------------------------------------------------
// Distributed grid barrier (no L2 invalidation; shared data read sc0/sc1).
// ---------------------------------------------------------------------------
DEV void bar_arrive(u32* __restrict__ slots, u32 n, int bid, int tid)
{
    asm volatile("s_waitcnt vmcnt(0)" ::: "memory");
    __syncthreads();
    if (tid == 0)
        __hip_atomic_store(&slots[bid], n, __ATOMIC_RELAXED, __HIP_MEMORY_SCOPE_AGENT);
}

DEV void bar_wait(u32* __restrict__ slots, u32 n, int tid)
{
    if (tid < 64) {
        for (;;) {
            u32 v0 = __hip_atomic_load(&slots[tid*4+0], __ATOMIC_RELAXED, __HIP_MEMORY_SCOPE_AGENT);
            u32 v1 = __hip_atomic_load(&slots[tid*4+1], __ATOMIC_RELAXED, __HIP_MEMORY_SCOPE_AGENT);
            u32 v2 = __hip_atomic_load(&slots[tid*4+2], __ATOMIC_RELAXED, __HIP_MEMORY_SCOPE_AGENT);
            u32 v3 = __hip_atomic_load(&slots[tid*4+3], __ATOMIC_RELAXED, __HIP_MEMORY_SCOPE_AGENT);
            bool ok = (v0 >= n) && (v1 >= n) && (v2 >= n) && (v3 >= n);
            if (__all(ok)) break;
            __builtin_amdgcn_s_sleep(1);
        }
    }
    __syncthreads();
}

// ---------------------------------------------------------------------------
// k_prep: fused one-shot prep.
//   [0,4096)      cvt Wih  -> Wih16
//   [4096,6144)   cvt Wao  -> Wao16
//   [6144,10240)  cvt enc  -> enc16
//   [10240,12256) gather emb rows -> xrow (bf16)
//   [12256,12512) transpose W_attn_in -> WT (bf16)
//   [12512,12544) init cF (fp32), hb buf0 (bf16)
// ---------------------------------------------------------------------------
__global__ void __launch_bounds__(256)
k_prep(const float* __restrict__ Wih, u16* __restrict__ Wih16,
       const float* __restrict__ Wao, u16* __restrict__ Wao16,
       const float* __restrict__ enc, u16* __restrict__ enc16,
       const int* __restrict__ tgt, const float* __restrict__ emb, u16* __restrict__ xrow,
       const float* __restrict__ Wai, u16* __restrict__ WT,
       const float* __restrict__ h0, const float* __restrict__ c0,
       float* __restrict__ cF, u16* __restrict__ hb)
{
    const int bid = blockIdx.x, tid = threadIdx.x;
    __shared__ u16 tl[64][65];
    if (bid < 10240) {
        const float* src; u16* dst; int i;
        if (bid < 4096)      { src = Wih; dst = Wih16; i = bid * 1024 + tid * 4; }
        else if (bid < 6144) { src = Wao; dst = Wao16; i = (bid - 4096) * 1024 + tid * 4; }
        else                 { src = enc; dst = enc16; i = (bid - 6144) * 1024 + tid * 4; }
        f32x4 v = *(const f32x4*)(src + i);
        short4v o;
        o[0]=(short)f2bf(v[0]); o[1]=(short)f2bf(v[1]);
        o[2]=(short)f2bf(v[2]); o[3]=(short)f2bf(v[3]);
        *(short4v*)(dst + i) = o;
    } else if (bid < 12256) {
        int r = bid - 10240;
        int t = r >> 5, b = r & 31;
        const float* src = emb + (size_t)tgt[b * 64 + t] * 1024;
        int j = tid * 4;
        f32x4 v = *(const f32x4*)(src + j);
        short4v o;
        o[0]=(short)f2bf(v[0]); o[1]=(short)f2bf(v[1]);
        o[2]=(short)f2bf(v[2]); o[3]=(short)f2bf(v[3]);
        *(short4v*)(xrow + (size_t)r * 1024 + j) = o;
    } else if (bid < 12512) {
        int tb = bid - 12256;
        int ti = tb >> 4, tj = tb & 15;
        int rr = tid >> 2, cc = (tid & 3) * 16;
        for (int i = 0; i < 16; ++i)
            tl[rr][cc + i] = f2bf(Wai[(size_t)(ti * 64 + rr) * 1024 + tj * 64 + cc + i]);
        __syncthreads();
        for (int i = 0; i < 16; ++i)
            WT[(size_t)(tj * 64 + rr) * 1024 + ti * 64 + cc + i] = tl[cc + i][rr];
    } else {
        int b = bid - 12512;
        int j = tid * 4;
        for (int i = 0; i < 4; ++i) {
            int k = j + i;
            float hv = (k < 512) ? h0[(size_t)b * 512 + k] : h0[(size_t)(32 + b) * 512 + (k - 512)];
            float cv = (k < 512) ? c0[(size_t)b * 512 + k] : c0[(size_t)(32 + b) * 512 + (k - 512)];
            cF[b * 1024 + k] = cv;
            hb[b * 1024 + k] = f2bf(hv);
        }
    }
}

// ---------------------------------------------------------------------------
// k_mm: fused xg-GEMM [0,2048) and M-GEMM [2048,3072)
// ---------------------------------------------------------------------------
__global__ void __launch_bounds__(256)
k_mm(const u16* __restrict__ xrow, const u16* __restrict__ Wih16,
     const float* __restrict__ bih, const float* __restrict__ bhh, u16* __restrict__ xg,
     const u16* __restrict__ enc16, const u16* __restrict__ WT, float* __restrict__ Mf)
{
    const int tid = threadIdx.x;
    const int wv = tid >> 6, l = tid & 63, lr = l & 15, lq = l >> 4;
    if (blockIdx.x < 2048) {
        const int bid = blockIdx.x;
        const int mt = bid & 31, nt = bid >> 5;
        const int r0 = mt * 64 + wv * 16;
        const int n0 = nt * 64;
        int r = r0 + lr;
        int rc = (r < 2016) ? r : 2015;
        const u16* arow = xrow + (size_t)rc * 1024;
        const u16* brow = Wih16 + (size_t)(n0 + lr) * 1024;
        f32x4 acc[4] = {{0,0,0,0},{0,0,0,0},{0,0,0,0},{0,0,0,0}};
        for (int k0 = 0; k0 < 1024; k0 += 32) {
            int ko = k0 + lq * 8;
            short8 av = *(const short8*)(arow + ko);
#pragma unroll
            for (int nf = 0; nf < 4; ++nf) {
                short8 bv = *(const short8*)(brow + (size_t)nf * 16 * 1024 + ko);
                acc[nf] = __builtin_amdgcn_mfma_f32_16x16x32_bf16(av, bv, acc[nf], 0, 0, 0);
            }
        }
#pragma unroll
        for (int nf = 0; nf < 4; ++nf) {
            int n = n0 + nf * 16 + lr;
            float bias = bih[n] + bhh[n];
#pragma unroll
            for (int q = 0; q < 4; ++q) {
                int rr = r0 + lq * 4 + q;
                if (rr < 2016) xg[(size_t)rr * 4096 + n] = f2bf(acc[nf][q] + bias);
            }
        }
    } else {
        const int bid = blockIdx.x - 2048;
        const int mt = bid & 63, nt = bid >> 6;
        const int r0 = mt * 64 + wv * 16;
        const int n0 = nt * 64;
        const u16* arow = enc16 + (size_t)(r0 + lr) * 1024;
        const u16* brow = WT + (size_t)(n0 + lr) * 1024;
        f32x4 acc[4] = {{0,0,0,0},{0,0,0,0},{0,0,0,0},{0,0,0,0}};
        for (int k0 = 0; k0 < 1024; k0 += 32) {
            int ko = k0 + lq * 8;
            short8 av = *(const short8*)(arow + ko);
#pragma unroll
            for (int nf = 0; nf < 4; ++nf) {
                short8 bv = *(const short8*)(brow + (size_t)nf * 16 * 1024 + ko);
                acc[nf] = __builtin_amdgcn_mfma_f32_16x16x32_bf16(av, bv, acc[nf], 0, 0, 0);
            }
        }
#pragma unroll
        for (int nf = 0; nf < 4; ++nf) {
            int n = n0 + nf * 16 + lr;
#pragma unroll
            for (int q = 0; q < 4; ++q)
                Mf[(size_t)(r0 + lq * 4 + q) * 1024 + n] = acc[nf][q];
        }
    }
}

// ---------------------------------------------------------------------------
// combine 16 half-chunk partials -> ctxA[tstore] (tid<32)
// ---------------------------------------------------------------------------
DEV void combine16(int b, int ch, int tstore, int tid, int slot,
                   const float* __restrict__ pCtx, const float* __restrict__ pMx,
                   const float* __restrict__ pSm, u16* __restrict__ ctxA)
{
    if (tid >= 32) return;
    const float* mx = pMx + (size_t)slot * 512 + b * 16;
    const float* sm = pSm + (size_t)slot * 512 + b * 16;
    const float* pc = pCtx + (size_t)slot * (32 * 16 * 1024) + (size_t)b * 16 * 1024;
    float m16[16], s16[16];
#pragma unroll
    for (int c = 0; c < 16; ++c) { m16[c] = ldg_f32(mx + c); s16[c] = ldg_f32(sm + c); }
    float gm = -1e30f;
#pragma unroll
    for (int c = 0; c < 16; ++c) gm = fmaxf(gm, m16[c]);
    float wsum = 0.f, e[16];
#pragma unroll
    for (int c = 0; c < 16; ++c) { e[c] = expf(m16[c] - gm); wsum += s16[c] * e[c]; }
    float inv = 1.f / wsum;
    int j = ch * 128 + tid * 4;
    f32x4 a = {0.f, 0.f, 0.f, 0.f};
#pragma unroll
    for (int c = 0; c < 16; ++c) {
        union { u64 q[2]; f32x4 v; } u;
        const u64* p = (const u64*)(pc + (size_t)c * 1024 + j);
        u.q[0] = ldg_u64(p); u.q[1] = ldg_u64(p + 1);
        float s = e[c] * inv;
        a[0] += u.v[0] * s; a[1] += u.v[1] * s; a[2] += u.v[2] * s; a[3] += u.v[3] * s;
    }
    short4v o4;
    o4[0] = (short)f2bf(a[0]); o4[1] = (short)f2bf(a[1]);
    o4[2] = (short)f2bf(a[2]); o4[3] = (short)f2bf(a[3]);
    *(short4v*)(ctxA + ((size_t)tstore * 32 + b) * 1024 + j) = o4;
}

// ---------------------------------------------------------------------------
// k_loop: wave-specialized persistent kernel.
//   waves 0-1: gates GEMM — W_hh fragment in REGISTERS, A-loads 16-deep pipeline
//   waves 2-3: attention (in-wave softmax) then LSTM
//   shadow after arrive: combine(t-2) + xg prefetch
// ---------------------------------------------------------------------------
#define ML_PITCH 1028
#define EL_PITCH 1032
#define ML_BYTES (16 * ML_PITCH * 4)
#define EL_BYTES (16 * EL_PITCH * 2)
#define DYN_BYTES (ML_BYTES + EL_BYTES)

__global__ void __launch_bounds__(256, 1)
k_loop(const u16* __restrict__ xg, const float* __restrict__ Mf,
       u16* __restrict__ ctxA, u16* __restrict__ hAll,
       u16* __restrict__ hb, float* __restrict__ hF, float* __restrict__ cF,
       float* __restrict__ pCtx, float* __restrict__ pMx, float* __restrict__ pSm,
       const float* __restrict__ enc, const float* __restrict__ Whh,
       const int* __restrict__ slen, float* __restrict__ out, u32* __restrict__ bar)
{
    const int bid = blockIdx.x, tid = threadIdx.x;
    const int wv = tid >> 6, l = tid & 63, lr = l & 15, lq = l >> 4;
    u32* slots = bar;

    extern __shared__ char smem[];
    float* Ml = (float*)smem;                 // [16][ML_PITCH]
    u16*   El = (u16*)(smem + ML_BYTES);      // [16][EL_PITCH]

    __shared__ float red[2][32][16];

    const int b_at = bid >> 3, ch = bid & 7, s0 = ch * 16;

    // ---- prologue ----
    // GEMM waves: W_hh fragment -> registers (16 x short8 per wave)
    short8 breg[16];
    if (wv < 2) {
        const float* wsrc = Whh + ((size_t)((lr >> 2) * 1024 + bid * 4 + (lr & 3))) * 1024
                                + wv * 512 + lq * 8;
#pragma unroll
        for (int ks = 0; ks < 16; ++ks)
            breg[ks] = cvt8(wsrc + ks * 32);
    }
    {   // M slice (fp32)
        int row = tid >> 4;
        const float* src = Mf + (size_t)(b_at * 128 + s0 + row) * 1024;
        float* dst = &Ml[row * ML_PITCH];
#pragma unroll
        for (int i = 0; i < 16; ++i) {
            int c = (tid & 15) * 4 + i * 64;
            *(f32x4*)(dst + c) = *(const f32x4*)(src + c);
        }
    }
    {   // enc slice (bf16)
        int row = tid >> 4;
        const float* src = enc + (size_t)(b_at * 128 + s0 + row) * 1024;
        u16* dst = &El[row * EL_PITCH];
#pragma unroll
        for (int i = 0; i < 16; ++i) {
            int c = (tid & 15) * 4 + i * 64;
            f32x4 v = *(const f32x4*)(src + c);
            short4v o;
            o[0]=(short)f2bf(v[0]); o[1]=(short)f2bf(v[1]);
            o[2]=(short)f2bf(v[2]); o[3]=(short)f2bf(v[3]);
            *(short4v*)(dst + c) = o;
        }
    }

    // LSTM locals (tid in [128,256)): batch lb, hidden col lkidx
    const int lb = tid & 31, lkk = (tid >> 5) - 4;
    const int lkidx = bid * 4 + lkk;
    float creg = 0.f;
    float xgv[4] = {0,0,0,0};
    if (tid >= 128) {
        creg = cF[lb * 1024 + lkidx];
#pragma unroll
        for (int g = 0; g < 4; ++g)
            xgv[g] = bf2f(xg[((size_t)lb) * 4096 + g * 1024 + lkidx]);   // t=0
    }
    int vlen = slen[b_at]; if (vlen < 1) vlen = 1;
    __syncthreads();

    for (int t = 0; t < 64; ++t) {
        if (t >= 1) bar_wait(slots, (u32)t, tid);

        if (t < 63 && wv < 2) {
            // ---- gates GEMM (waves 0-1, K split 2-way, 16-deep pipeline) ----
            const u16* hrd = hb + (size_t)(t & 1) * (32 * 1024);
            const u16* p0 = hrd + lr * 1024 + wv * 512 + lq * 8;
            const u16* p1 = p0 + 16 * 1024;
            i32x4 a0b[16], a1b[16];
#pragma unroll
            for (int ks = 0; ks < 16; ++ks) {
                ldcc4i(&a0b[ks], p0 + ks * 32);
                ldcc4i(&a1b[ks], p1 + ks * 32);
            }
            f32x4 acc0 = {0,0,0,0}, acc1 = {0,0,0,0};
#pragma unroll
            for (int ks = 0; ks < 16; ++ks) {
                asm volatile("s_waitcnt vmcnt(%0)" :: "i"(30 - 2 * ks) : "memory");
                __builtin_amdgcn_sched_barrier(0);
                acc0 = __builtin_amdgcn_mfma_f32_16x16x32_bf16(as_s8(a0b[ks]), breg[ks], acc0, 0, 0, 0);
                acc1 = __builtin_amdgcn_mfma_f32_16x16x32_bf16(as_s8(a1b[ks]), breg[ks], acc1, 0, 0, 0);
            }
#pragma unroll
            for (int q = 0; q < 4; ++q) {
                red[wv][lq * 4 + q][lr] = acc0[q];
                red[wv][16 + lq * 4 + q][lr] = acc1[q];
            }
        }

        if (t >= 1 && wv >= 2) {
            // ---- attention for h_t (waves 2-3, fully in-wave) ----
            const int w = wv - 2;
            const int lane = l;
            const float* hrow = hF + (size_t)(t & 1) * (32 * 1024) + b_at * 1024;
            f32x4 hreg[4];
            ldcc4f(&hreg[0], hrow + 0 * 256 + lane * 4);
            ldcc4f(&hreg[1], hrow + 1 * 256 + lane * 4);
            ldcc4f(&hreg[2], hrow + 2 * 256 + lane * 4);
            ldcc4f(&hreg[3], hrow + 3 * 256 + lane * 4);
            asm volatile("s_waitcnt vmcnt(0)" ::: "memory");
            __builtin_amdgcn_sched_barrier(0);
            float part[8];
#pragma unroll
            for (int r = 0; r < 8; ++r) {
                const float* mrow = &Ml[(w * 8 + r) * ML_PITCH];
                float s = 0.f;
#pragma unroll
                for (int c = 0; c < 4; ++c) {
                    f32x4 m4 = *(const f32x4*)(mrow + c * 256 + lane * 4);
                    s += m4[0]*hreg[c][0] + m4[1]*hreg[c][1] + m4[2]*hreg[c][2] + m4[3]*hreg[c][3];
                }
                part[r] = s;
            }
#pragma unroll
            for (int d = 1; d < 64; d <<= 1) {
#pragma unroll
                for (int r = 0; r < 8; ++r) part[r] += __shfl_xor(part[r], d);
            }
            int sgb = s0 + w * 8;
            float mc = -1e30f;
#pragma unroll
            for (int r = 0; r < 8; ++r) {
                part[r] = (sgb + r < vlen) ? part[r] : -1e30f;
                mc = fmaxf(mc, part[r]);
            }
            float e8[8]; float psum = 0.f;
#pragma unroll
            for (int r = 0; r < 8; ++r) {
                e8[r] = (part[r] > -1e29f) ? expf(part[r] - mc) : 0.f;
                psum += e8[r];
            }
            f32x4 ca[4] = {{0,0,0,0},{0,0,0,0},{0,0,0,0},{0,0,0,0}};
#pragma unroll
            for (int r = 0; r < 8; ++r) {
                float p = e8[r];
                const u16* erow = &El[(w * 8 + r) * EL_PITCH];
#pragma unroll
                for (int c = 0; c < 4; ++c) {
                    short4v e4 = *(const short4v*)(erow + c * 256 + lane * 4);
                    ca[c][0] += p * bf2f((u16)e4[0]);
                    ca[c][1] += p * bf2f((u16)e4[1]);
                    ca[c][2] += p * bf2f((u16)e4[2]);
                    ca[c][3] += p * bf2f((u16)e4[3]);
                }
            }
            float* pd = pCtx + (size_t)(t & 3) * (32 * 16 * 1024)
                             + (size_t)(b_at * 16 + ch * 2 + w) * 1024;
#pragma unroll
            for (int c = 0; c < 4; ++c) {
                union { f32x4 v; u64 q[2]; } cu; cu.v = ca[c];
                u64* p = (u64*)(pd + c * 256 + lane * 4);
                stg_u64(p, cu.q[0]);
                stg_u64(p + 1, cu.q[1]);
            }
            if (lane == 0) {
                stg_f32(&pMx[(size_t)(t & 3) * 512 + b_at * 16 + ch * 2 + w], mc);
                stg_f32(&pSm[(size_t)(t & 3) * 512 + b_at * 16 + ch * 2 + w], psum);
            }
        }
        __syncthreads();

        if (t < 63 && tid >= 128) {
            // ---- LSTM elementwise ----
            float G[4];
#pragma unroll
            for (int g = 0; g < 4; ++g) {
                int n = g * 4 + lkk;
                G[g] = red[0][lb][n] + red[1][lb][n] + xgv[g];
            }
            float iS = sigm(G[0]), fS = sigm(G[1]), gT = tanhf(G[2]), oS = sigm(G[3]);
            float cn = fS * creg + iS * gT;
            float hn = oS * tanhf(cn);
            creg = cn;
            u16 h16 = f2bf(hn);
            int sl = (t + 1) & 1;
            stg_f32(&hF[(size_t)sl * (32 * 1024) + lb * 1024 + lkidx], hn);
            stg_u16(&hb[(size_t)sl * (32 * 1024) + lb * 1024 + lkidx], h16);
            hAll[((size_t)t * 32 + lb) * 1024 + lkidx] = h16;
        }

        bar_arrive(slots, (u32)(t + 1), bid, tid);

        // ---- shadow: combine + xg prefetch overlap barrier propagation ----
        if (t >= 2)
            combine16(b_at, ch, t - 2, tid, (t - 1) & 3, pCtx, pMx, pSm, ctxA);
        if (t < 62 && tid >= 128) {
#pragma unroll
            for (int g = 0; g < 4; ++g)
                xgv[g] = bf2f(xg[((size_t)(t + 1) * 32 + lb) * 4096 + g * 1024 + lkidx]);
        }
    }

    bar_wait(slots, 64u, tid);
    combine16(b_at, ch, 62, tid, 3, pCtx, pMx, pSm, ctxA);
    if (bid >= 32 && bid < 64) {
        int b = bid - 32, j = tid * 4;
#pragma unroll
        for (int i = 0; i < 4; ++i)
            out[2064384 + b * 1024 + j + i] = ldg_f32(&hF[(size_t)1 * (32 * 1024) + b * 1024 + j + i]);
    }
    if (tid >= 128)
        out[2064384 + 32768 + lb * 1024 + lkidx] = creg;
}

// ---------------------------------------------------------------------------
__global__ void __launch_bounds__(256)
k_out(const u16* __restrict__ ctxA, const u16* __restrict__ hAll,
      const u16* __restrict__ Wao16, float* __restrict__ out)
{
    const int bid = blockIdx.x, tid = threadIdx.x;
    const int mt = bid & 31, nt = bid >> 5;
    const int wv = tid >> 6, l = tid & 63, lr = l & 15, lq = l >> 4;
    const int r0 = mt * 64 + wv * 16;
    const int n0 = nt * 64;
    int r = r0 + lr;
    int rc = (r < 2016) ? r : 2015;
    const u16* arc = ctxA + (size_t)rc * 1024;
    const u16* arh = hAll + (size_t)rc * 1024;
    const u16* brow = Wao16 + (size_t)(n0 + lr) * 2048;
    f32x4 acc[4] = {{0,0,0,0},{0,0,0,0},{0,0,0,0},{0,0,0,0}};
    for (int k0 = 0; k0 < 2048; k0 += 32) {
        int ko = k0 + lq * 8;
        short8 av = (k0 < 1024) ? *(const short8*)(arc + ko)
                                : *(const short8*)(arh + (ko - 1024));
#pragma unroll
        for (int nf = 0; nf < 4; ++nf) {
            short8 bv = *(const short8*)(brow + (size_t)nf * 16 * 2048 + ko);
            acc[nf] = __builtin_amdgcn_mfma_f32_16x16x32_bf16(av, bv, acc[nf], 0, 0, 0);
        }
    }
#pragma unroll
    for (int nf = 0; nf < 4; ++nf) {
        int n = n0 + nf * 16 + lr;
#pragma unroll
        for (int q = 0; q < 4; ++q) {
            int rr = r0 + lq * 4 + q;
            if (rr < 2016) {
                int t = rr >> 5, b = rr & 31;
                out[(size_t)b * 64512 + t * 1024 + n] = tanhf(acc[nf][q]);
            }
        }
    }
}

// ---------------------------------------------------------------------------
extern "C" void kernel_launch(void* const* d_in, const int* in_sizes, int n_in,
                              void* d_out, int out_size, void* d_ws, size_t ws_size,
                              hipStream_t stream)
{
    (void)in_sizes; (void)n_in; (void)out_size; (void)ws_size;
    const int*   tgt  = (const int*)d_in[0];
    const float* h0   = (const float*)d_in[1];
    const float* c0   = (const float*)d_in[2];
    const float* enc  = (const float*)d_in[3];
    const int*   slen = (const int*)d_in[4];
    const float* emb  = (const float*)d_in[5];
    const float* Wih  = (const float*)d_in[6];
    const float* Whh  = (const float*)d_in[7];
    const float* bih  = (const float*)d_in[8];
    const float* bhh  = (const float*)d_in[9];
    const float* Wai  = (const float*)d_in[10];
    const float* Wao  = (const float*)d_in[11];
    float* out = (float*)d_out;

    char* ws = (char*)d_ws;
    size_t off = 0;
    auto alloc = [&](size_t bytes) -> char* {
        char* p = ws + off; off += (bytes + 255) & ~(size_t)255; return p;
    };
    u16*   xg    = (u16*)  alloc(63UL * 32 * 4096 * 2);
    float* Mf    = (float*)alloc(4096UL * 1024 * 4);
    u16*   WT    = (u16*)  alloc(1024UL * 1024 * 2);
    u16*   Wih16 = (u16*)  alloc(4096UL * 1024 * 2);
    u16*   Wao16 = (u16*)  alloc(1024UL * 2048 * 2);
    u16*   ctxA  = (u16*)  alloc(2016UL * 1024 * 2);
    u16*   hAll  = (u16*)  alloc(2016UL * 1024 * 2);
    u16*   hb    = (u16*)  alloc(2UL * 32 * 1024 * 2);
    float* hF    = (float*)alloc(2UL * 32 * 1024 * 4);
    float* cF    = (float*)alloc(32UL * 1024 * 4);
    float* pCtx  = (float*)alloc(4UL * 32 * 16 * 1024 * 4);
    float* pMx   = (float*)alloc(4UL * 512 * 4);
    float* pSm   = (float*)alloc(4UL * 512 * 4);
    u16*   xrow  = (u16*)  alloc(2016UL * 1024 * 2);
    u16*   enc16 = (u16*)  alloc(4096UL * 1024 * 2);
    u32*   bar   = (u32*)  alloc(2048);

    static int lds_set = 0;
    if (!lds_set) {
        (void)hipFuncSetAttribute((const void*)k_loop,
                                  hipFuncAttributeMaxDynamicSharedMemorySize, DYN_BYTES);
        lds_set = 1;
    }

    hipMemsetAsync(bar, 0, 2048, stream);
    hipLaunchKernelGGL(k_prep, dim3(12544), dim3(256), 0, stream,
                       Wih, Wih16, Wao, Wao16, enc, enc16, tgt, emb, xrow,
                       Wai, WT, h0, c0, cF, hb);
    hipLaunchKernelGGL(k_mm, dim3(3072), dim3(256), 0, stream,
                       xrow, Wih16, bih, bhh, xg, enc16, WT, Mf);

    void* kargs[] = { (void*)&xg, (void*)&Mf, (void*)&ctxA, (void*)&hAll, (void*)&hb,
                      (void*)&hF, (void*)&cF, (void*)&pCtx, (void*)&pMx, (void*)&pSm,
                      (void*)&enc, (void*)&Whh, (void*)&slen, (void*)&out, (void*)&bar };
    hipLaunchCooperativeKernel((const void*)k_loop, dim3(256), dim3(256), kargs, DYN_BYTES, stream);

    hipLaunchKernelGGL(k_out, dim3(512), dim3(256), 0, stream, ctxA, hAll, Wao16, out);
}